// Round 1
// baseline (766.792 us; speedup 1.0000x reference)
//
#include <hip/hip_runtime.h>
#include <math.h>

// Problem constants (B,C,H,W = 4,128,64,64)
constexpr int Bn  = 4;
constexpr int Cn  = 128;
constexpr int C8n = 16;
constexpr int Nn  = 4096;   // H*W
constexpr int QB  = 32;     // queries per block
constexpr int KB  = 64;     // keys per tile

// ---------------------------------------------------------------------------
// Kernel 1: q/k/v projection. One (b,n) column per thread.
// x column -> 128 registers; W reads are wave-uniform (scalar-cache path).
// ---------------------------------------------------------------------------
__global__ __launch_bounds__(64) void qkv_kernel(
    const float* __restrict__ x,
    const float* __restrict__ Wq, const float* __restrict__ bq,
    const float* __restrict__ Wk, const float* __restrict__ bk,
    const float* __restrict__ Wv, const float* __restrict__ bv,
    float* __restrict__ qo, float* __restrict__ ko, float* __restrict__ vo)
{
    const int gid = blockIdx.x * 64 + threadIdx.x;   // 0 .. B*N-1
    const int b = gid >> 12;          // / Nn
    const int n = gid & (Nn - 1);     // % Nn

    float xc[Cn];
    #pragma unroll
    for (int c = 0; c < Cn; ++c)
        xc[c] = x[((size_t)(b * Cn + c)) * Nn + n];   // coalesced across threads

    for (int o = 0; o < C8n; ++o) {
        float acc = bq[o];
        #pragma unroll
        for (int c = 0; c < Cn; ++c) acc += Wq[o * Cn + c] * xc[c];
        qo[((size_t)(b * C8n + o)) * Nn + n] = acc;
    }
    for (int o = 0; o < C8n; ++o) {
        float acc = bk[o];
        #pragma unroll
        for (int c = 0; c < Cn; ++c) acc += Wk[o * Cn + c] * xc[c];
        ko[((size_t)(b * C8n + o)) * Nn + n] = acc;
    }
    for (int o = 0; o < Cn; ++o) {
        float acc = bv[o];
        #pragma unroll
        for (int c = 0; c < Cn; ++c) acc += Wv[o * Cn + c] * xc[c];
        vo[((size_t)(b * Cn + o)) * Nn + n] = acc;
    }
}

// ---------------------------------------------------------------------------
// Kernel 2: flash attention, fp32. Block = 256 thr, QB=32 queries, KB=64 keys.
// ---------------------------------------------------------------------------
__global__ __launch_bounds__(256) void attn_kernel(
    const float* __restrict__ q, const float* __restrict__ k,
    const float* __restrict__ v, const float* __restrict__ x,
    const float* __restrict__ gamma_p, float* __restrict__ out)
{
    __shared__ float q_s[C8n][33];    // [c][qi], pad 33: bank = (c+qi)%32
    __shared__ float k_s[C8n][68];    // [c][j],  pad 68 keeps float4 alignment
    __shared__ float v_s[Cn][68];     // [c][j]
    __shared__ float p_s[QB][65];     // [qi][j], pad 65: bank = (qi+j)%32
    __shared__ float pm[8][33];
    __shared__ float ps[8][33];
    __shared__ float row_f[QB], m_s[QB], l_s[QB];

    const int tid = threadIdx.x;
    const int b   = blockIdx.y;
    const int q0  = blockIdx.x * QB;
    const int qi  = tid & 31;
    const int grp = tid >> 5;          // 0..7

    // load Q block (16 x 32)
    for (int idx = tid; idx < C8n * QB; idx += 256) {
        int c = idx >> 5, qq = idx & 31;
        q_s[c][qq] = q[((size_t)(b * C8n + c)) * Nn + q0 + qq];
    }
    if (tid < QB) { m_s[tid] = -INFINITY; l_s[tid] = 0.0f; }

    float acc[16];
    #pragma unroll
    for (int i = 0; i < 16; ++i) acc[i] = 0.0f;

    const float* kb = k + (size_t)b * C8n * Nn;
    const float* vb = v + (size_t)b * Cn * Nn;

    for (int j0 = 0; j0 < Nn; j0 += KB) {
        __syncthreads();   // prev-iter PV done reading v_s/p_s (also covers init)

        // stage K tile: 16x64 floats = 256 float4 (1 per thread)
        {
            int c = tid >> 4, jv = tid & 15;
            float4 t = *reinterpret_cast<const float4*>(&kb[(size_t)c * Nn + j0 + jv * 4]);
            *reinterpret_cast<float4*>(&k_s[c][jv * 4]) = t;
        }
        // stage V tile: 128x64 floats = 2048 float4 (8 per thread)
        #pragma unroll
        for (int r = 0; r < 8; ++r) {
            int idx = r * 256 + tid;
            int c = idx >> 4, jv = idx & 15;
            float4 t = *reinterpret_cast<const float4*>(&vb[(size_t)c * Nn + j0 + jv * 4]);
            *reinterpret_cast<float4*>(&v_s[c][jv * 4]) = t;
        }
        __syncthreads();

        // scores: thread (qi, grp) computes 8 keys j = grp*8 .. +7, dot over 16 ch
        float s[8];
        #pragma unroll
        for (int jj = 0; jj < 8; ++jj) s[jj] = 0.0f;
        #pragma unroll
        for (int c = 0; c < C8n; ++c) {
            float qv = q_s[c][qi];
            float4 k0 = *reinterpret_cast<float4*>(&k_s[c][grp * 8]);
            float4 k1 = *reinterpret_cast<float4*>(&k_s[c][grp * 8 + 4]);
            s[0] += qv * k0.x; s[1] += qv * k0.y; s[2] += qv * k0.z; s[3] += qv * k0.w;
            s[4] += qv * k1.x; s[5] += qv * k1.y; s[6] += qv * k1.z; s[7] += qv * k1.w;
        }
        float mloc = s[0];
        #pragma unroll
        for (int jj = 1; jj < 8; ++jj) mloc = fmaxf(mloc, s[jj]);
        pm[grp][qi] = mloc;
        __syncthreads();

        // per-row online-max bookkeeping (lanes 0..31 of wave 0)
        if (tid < QB) {
            float mt = pm[0][tid];
            #pragma unroll
            for (int g = 1; g < 8; ++g) mt = fmaxf(mt, pm[g][tid]);
            float mo = m_s[tid];
            float mn = fmaxf(mo, mt);
            row_f[tid] = __expf(mo - mn);   // first tile: exp(-inf) = 0
            m_s[tid]  = mn;
        }
        __syncthreads();

        // p = exp(s - m_new); partial row sums
        float mn = m_s[qi];
        float sum = 0.0f;
        #pragma unroll
        for (int jj = 0; jj < 8; ++jj) {
            float p = __expf(s[jj] - mn);
            p_s[qi][grp * 8 + jj] = p;
            sum += p;
        }
        ps[grp][qi] = sum;
        __syncthreads();

        if (tid < QB) {
            float t = ps[0][tid];
            #pragma unroll
            for (int g = 1; g < 8; ++g) t += ps[g][tid];
            l_s[tid] = l_s[tid] * row_f[tid] + t;
        }

        // PV: thread (qi, grp) owns query qi, channels c0..c0+15
        const int c0 = grp * 16;
        float f = row_f[qi];
        #pragma unroll
        for (int cc = 0; cc < 16; ++cc) acc[cc] *= f;
        for (int j = 0; j < KB; j += 4) {
            float p0 = p_s[qi][j],     p1 = p_s[qi][j + 1];
            float p2 = p_s[qi][j + 2], p3 = p_s[qi][j + 3];
            #pragma unroll
            for (int cc = 0; cc < 16; ++cc) {
                float4 v4 = *reinterpret_cast<float4*>(&v_s[c0 + cc][j]);
                acc[cc] += p0 * v4.x + p1 * v4.y + p2 * v4.z + p3 * v4.w;
            }
        }
    }
    __syncthreads();

    const float linv = 1.0f / l_s[qi];
    const float g = gamma_p[0];
    const int c0 = grp * 16;
    #pragma unroll
    for (int cc = 0; cc < 16; ++cc) {
        size_t idx = ((size_t)(b * Cn + c0 + cc)) * Nn + q0 + qi;
        out[idx] = g * (acc[cc] * linv) + x[idx];
    }
}

// ---------------------------------------------------------------------------
extern "C" void kernel_launch(void* const* d_in, const int* in_sizes, int n_in,
                              void* d_out, int out_size, void* d_ws, size_t ws_size,
                              hipStream_t stream)
{
    const float* x     = (const float*)d_in[0];
    const float* Wq    = (const float*)d_in[1];
    const float* bq    = (const float*)d_in[2];
    const float* Wk    = (const float*)d_in[3];
    const float* bk    = (const float*)d_in[4];
    const float* Wv    = (const float*)d_in[5];
    const float* bv    = (const float*)d_in[6];
    const float* gamma = (const float*)d_in[7];
    float* out = (float*)d_out;

    // workspace layout: q (B*16*N) | k (B*16*N) | v (B*128*N)  = 10.5 MB
    float* qw = (float*)d_ws;
    float* kw = qw + (size_t)Bn * C8n * Nn;
    float* vw = kw + (size_t)Bn * C8n * Nn;

    qkv_kernel<<<dim3(Bn * Nn / 64), dim3(64), 0, stream>>>(
        x, Wq, bq, Wk, bk, Wv, bv, qw, kw, vw);

    attn_kernel<<<dim3(Nn / QB, Bn), dim3(256), 0, stream>>>(
        qw, kw, vw, x, gamma, out);
}

// Round 2
// 203.358 us; speedup vs baseline: 3.7706x; 3.7706x over previous
//
#include <hip/hip_runtime.h>
#include <math.h>

typedef __attribute__((ext_vector_type(8))) short bf16x8;
typedef __attribute__((ext_vector_type(16))) float f32x16;

constexpr int Bn = 4, Cn = 128, C8n = 16, Nn = 4096;

__device__ inline unsigned short f2bf(float f) {
    unsigned u = __builtin_bit_cast(unsigned, f);
    u += 0x7fff + ((u >> 16) & 1);          // round-to-nearest-even
    return (unsigned short)(u >> 16);
}
__device__ inline unsigned pack2(float a, float b) {
    return (unsigned)f2bf(a) | ((unsigned)f2bf(b) << 16);
}

// ---------------------------------------------------------------------------
// Kernel 1: qkv projection, fp32 math, bf16 outputs.
// qT,kT stored [b][n][c8] (transposed, 16B/row = one MFMA frag load).
// v stored [b][c][n].
// Block: 320 threads = 5 waves; wave 0 -> q(16)+k(16) rows, waves 1-4 -> v.
// ---------------------------------------------------------------------------
__global__ __launch_bounds__(320) void qkv_kernel(
    const float* __restrict__ x,
    const float* __restrict__ Wq, const float* __restrict__ bq,
    const float* __restrict__ Wk, const float* __restrict__ bk,
    const float* __restrict__ Wv, const float* __restrict__ bv,
    unsigned short* __restrict__ qT, unsigned short* __restrict__ kT,
    unsigned short* __restrict__ vv)
{
    __shared__ float xs[Cn][64];
    const int tid = threadIdx.x;
    const int b  = blockIdx.x >> 6;
    const int n0 = (blockIdx.x & 63) << 6;

    for (int idx = tid; idx < Cn * 16; idx += 320) {
        int c = idx >> 4, f4 = idx & 15;
        float4 t = *reinterpret_cast<const float4*>(
            &x[((size_t)(b * Cn + c)) * Nn + n0 + f4 * 4]);
        *reinterpret_cast<float4*>(&xs[c][f4 * 4]) = t;
    }
    __syncthreads();

    const int wv = tid >> 6, lane = tid & 63;
    const float *base0, *base1, *bia0, *bia1;
    if (wv == 0) { base0 = Wq; bia0 = bq; base1 = Wk; bia1 = bk; }
    else {
        base0 = Wv + (size_t)(wv - 1) * 32 * Cn; bia0 = bv + (wv - 1) * 32;
        base1 = base0 + 16 * Cn;                 bia1 = bia0 + 16;
    }
    float acc[32];
    #pragma unroll
    for (int j = 0; j < 16; ++j) acc[j] = bia0[j];
    #pragma unroll
    for (int j = 0; j < 16; ++j) acc[16 + j] = bia1[j];

    for (int c = 0; c < Cn; c += 4) {
        float x0 = xs[c][lane], x1 = xs[c + 1][lane];
        float x2 = xs[c + 2][lane], x3 = xs[c + 3][lane];
        #pragma unroll
        for (int j = 0; j < 16; ++j) {
            float4 w = *reinterpret_cast<const float4*>(&base0[j * Cn + c]);
            acc[j] = fmaf(w.x, x0, fmaf(w.y, x1, fmaf(w.z, x2, fmaf(w.w, x3, acc[j]))));
        }
        #pragma unroll
        for (int j = 0; j < 16; ++j) {
            float4 w = *reinterpret_cast<const float4*>(&base1[j * Cn + c]);
            acc[16 + j] = fmaf(w.x, x0, fmaf(w.y, x1, fmaf(w.z, x2, fmaf(w.w, x3, acc[16 + j]))));
        }
    }

    if (wv == 0) {
        unsigned qw[8], kw[8];
        #pragma unroll
        for (int j = 0; j < 8; ++j) qw[j] = pack2(acc[2 * j], acc[2 * j + 1]);
        #pragma unroll
        for (int j = 0; j < 8; ++j) kw[j] = pack2(acc[16 + 2 * j], acc[16 + 2 * j + 1]);
        size_t off = ((size_t)b * Nn + n0 + lane) * C8n;
        *reinterpret_cast<uint4*>(&qT[off])     = make_uint4(qw[0], qw[1], qw[2], qw[3]);
        *reinterpret_cast<uint4*>(&qT[off + 8]) = make_uint4(qw[4], qw[5], qw[6], qw[7]);
        *reinterpret_cast<uint4*>(&kT[off])     = make_uint4(kw[0], kw[1], kw[2], kw[3]);
        *reinterpret_cast<uint4*>(&kT[off + 8]) = make_uint4(kw[4], kw[5], kw[6], kw[7]);
    } else {
        const int c0 = (wv - 1) * 32;
        #pragma unroll
        for (int j = 0; j < 32; ++j)
            vv[((size_t)(b * Cn + c0 + j)) * Nn + n0 + lane] = f2bf(acc[j]);
    }
}

// ---------------------------------------------------------------------------
// Kernel 2: flash attention on MFMA 32x32x16 bf16, swapped scores (S' = K^T Q).
// Block: 4 waves; each wave = same 32 queries, 1024-key partition; LDS merge.
// ---------------------------------------------------------------------------
__global__ __launch_bounds__(256) void attn_kernel(
    const unsigned short* __restrict__ qT, const unsigned short* __restrict__ kT,
    const unsigned short* __restrict__ vv, const float* __restrict__ x,
    const float* __restrict__ gamma_p, float* __restrict__ out)
{
    __shared__ float slot[2][4][16][64];
    __shared__ float mls[2][2][64];

    const int tid = threadIdx.x, wv = tid >> 6, lane = tid & 63;
    const int col = lane & 31, half = lane >> 5;
    const int q0 = blockIdx.x * 32, b = blockIdx.y;

    // Q B-frag: qT[b][q0+col][8*half .. +7]
    bf16x8 qf = *reinterpret_cast<const bf16x8*>(
        &qT[((size_t)b * Nn + q0 + col) * C8n + 8 * half]);

    f32x16 acc0 = {}, acc1 = {}, acc2 = {}, acc3 = {};
    float m_run = -INFINITY, l_run = 0.0f;
    const unsigned short* kb = kT + (size_t)b * Nn * C8n;
    const unsigned short* vb = vv + (size_t)b * Cn * Nn;

    for (int kt = 0; kt < 32; ++kt) {
        const int j0 = wv * 1024 + kt * 32;
        bf16x8 kf = *reinterpret_cast<const bf16x8*>(
            &kb[(size_t)(j0 + col) * C8n + 8 * half]);
        f32x16 zz = {};
        f32x16 s = __builtin_amdgcn_mfma_f32_32x32x16_bf16(kf, qf, zz, 0, 0, 0);

        // column-wise (over 32 keys) max: 16 in-lane + cross-half swap
        float t0 = fmaxf(fmaxf(fmaxf(s[0], s[1]), fmaxf(s[2], s[3])),
                         fmaxf(fmaxf(s[4], s[5]), fmaxf(s[6], s[7])));
        float t1 = fmaxf(fmaxf(fmaxf(s[8], s[9]), fmaxf(s[10], s[11])),
                         fmaxf(fmaxf(s[12], s[13]), fmaxf(s[14], s[15])));
        float tmax = fmaxf(t0, t1);
        tmax = fmaxf(tmax, __shfl_xor(tmax, 32));
        float m_new = fmaxf(m_run, tmax);
        float fs = __expf(m_run - m_new);   // first tile: exp(-inf)=0
        m_run = m_new;

        float p[16]; float psum = 0.0f;
        #pragma unroll
        for (int r = 0; r < 16; ++r) { p[r] = __expf(s[r] - m_new); psum += p[r]; }
        psum += __shfl_xor(psum, 32);
        l_run = l_run * fs + psum;
        acc0 *= fs; acc1 *= fs; acc2 *= fs; acc3 *= fs;

        // P B-frags: key row (r&3)+8*(r>>2)+4*half at col; half-exchange
        bf16x8 pf0, pf1;
        {
            unsigned lo0 = pack2(p[0], p[1]), lo1 = pack2(p[2], p[3]);
            unsigned hi0 = pack2(p[4], p[5]), hi1 = pack2(p[6], p[7]);
            unsigned s0 = half ? lo0 : hi0, s1 = half ? lo1 : hi1;
            unsigned r0 = (unsigned)__shfl_xor((int)s0, 32);
            unsigned r1 = (unsigned)__shfl_xor((int)s1, 32);
            uint4 u = make_uint4(half ? r0 : lo0, half ? r1 : lo1,
                                 half ? hi0 : r0, half ? hi1 : r1);
            pf0 = __builtin_bit_cast(bf16x8, u);
        }
        {
            unsigned lo0 = pack2(p[8], p[9]),  lo1 = pack2(p[10], p[11]);
            unsigned hi0 = pack2(p[12], p[13]), hi1 = pack2(p[14], p[15]);
            unsigned s0 = half ? lo0 : hi0, s1 = half ? lo1 : hi1;
            unsigned r0 = (unsigned)__shfl_xor((int)s0, 32);
            unsigned r1 = (unsigned)__shfl_xor((int)s1, 32);
            uint4 u = make_uint4(half ? r0 : lo0, half ? r1 : lo1,
                                 half ? hi0 : r0, half ? hi1 : r1);
            pf1 = __builtin_bit_cast(bf16x8, u);
        }

        // PV: A = V[32ch x 16key] (one dwordx4/lane), B = P-frag
        const unsigned short* vt = vb + j0 + 8 * half;
        #define PVSTEP(CT, ACC) { \
            const unsigned short* vr = vt + (size_t)(32 * CT + col) * Nn; \
            bf16x8 va = *reinterpret_cast<const bf16x8*>(vr); \
            bf16x8 vbb = *reinterpret_cast<const bf16x8*>(vr + 16); \
            ACC = __builtin_amdgcn_mfma_f32_32x32x16_bf16(va, pf0, ACC, 0, 0, 0); \
            ACC = __builtin_amdgcn_mfma_f32_32x32x16_bf16(vbb, pf1, ACC, 0, 0, 0); }
        PVSTEP(0, acc0) PVSTEP(1, acc1) PVSTEP(2, acc2) PVSTEP(3, acc3)
        #undef PVSTEP
    }

    // ---- merge 4 key-partitions: tree via LDS ----
    #define STORE_SLOT(SL) { \
        mls[SL][0][lane] = m_run; mls[SL][1][lane] = l_run; \
        _Pragma("unroll") for (int r = 0; r < 16; ++r) { \
            slot[SL][0][r][lane] = acc0[r]; slot[SL][1][r][lane] = acc1[r]; \
            slot[SL][2][r][lane] = acc2[r]; slot[SL][3][r][lane] = acc3[r]; } }

    #define MERGE_SLOT(SL) { \
        float m_i = mls[SL][0][lane], l_i = mls[SL][1][lane]; \
        float M = fmaxf(m_run, m_i); \
        float fo = __expf(m_run - M), fi = __expf(m_i - M); \
        m_run = M; l_run = l_run * fo + l_i * fi; \
        _Pragma("unroll") for (int r = 0; r < 16; ++r) { \
            acc0[r] = acc0[r] * fo + slot[SL][0][r][lane] * fi; \
            acc1[r] = acc1[r] * fo + slot[SL][1][r][lane] * fi; \
            acc2[r] = acc2[r] * fo + slot[SL][2][r][lane] * fi; \
            acc3[r] = acc3[r] * fo + slot[SL][3][r][lane] * fi; } }

    if (wv == 1 || wv == 3) STORE_SLOT(wv >> 1);
    __syncthreads();
    if (wv == 0 || wv == 2) MERGE_SLOT(wv >> 1);
    __syncthreads();
    if (wv == 2) STORE_SLOT(0);
    __syncthreads();
    if (wv == 0) {
        MERGE_SLOT(0);
        const float g = gamma_p[0], inv = 1.0f / l_run;
        #define WB(CT, ACC) { _Pragma("unroll") for (int r = 0; r < 16; ++r) { \
            int ch = 32 * CT + (r & 3) + 8 * (r >> 2) + 4 * half; \
            size_t idx = ((size_t)(b * Cn + ch)) * Nn + q0 + col; \
            out[idx] = g * (ACC[r] * inv) + x[idx]; } }
        WB(0, acc0) WB(1, acc1) WB(2, acc2) WB(3, acc3)
        #undef WB
    }
    #undef STORE_SLOT
    #undef MERGE_SLOT
}

// ---------------------------------------------------------------------------
extern "C" void kernel_launch(void* const* d_in, const int* in_sizes, int n_in,
                              void* d_out, int out_size, void* d_ws, size_t ws_size,
                              hipStream_t stream)
{
    const float* x     = (const float*)d_in[0];
    const float* Wq    = (const float*)d_in[1];
    const float* bq    = (const float*)d_in[2];
    const float* Wk    = (const float*)d_in[3];
    const float* bk    = (const float*)d_in[4];
    const float* Wv    = (const float*)d_in[5];
    const float* bv    = (const float*)d_in[6];
    const float* gamma = (const float*)d_in[7];
    float* out = (float*)d_out;

    // ws: qT (512 KB) | kT (512 KB) | v (4 MB), all bf16
    unsigned short* qTw = (unsigned short*)d_ws;
    unsigned short* kTw = qTw + (size_t)Bn * Nn * C8n;
    unsigned short* vw  = kTw + (size_t)Bn * Nn * C8n;

    qkv_kernel<<<dim3(256), dim3(320), 0, stream>>>(
        x, Wq, bq, Wk, bk, Wv, bv, qTw, kTw, vw);

    attn_kernel<<<dim3(Nn / 32, Bn), dim3(256), 0, stream>>>(
        qTw, kTw, vw, x, gamma, out);
}

// Round 3
// 156.964 us; speedup vs baseline: 4.8852x; 1.2956x over previous
//
#include <hip/hip_runtime.h>
#include <math.h>

typedef __attribute__((ext_vector_type(8))) short bf16x8;
typedef __attribute__((ext_vector_type(16))) float f32x16;

constexpr int Bn = 4, Cn = 128, C8n = 16, Nn = 4096;

#if __has_builtin(__builtin_amdgcn_exp2f)
#define EXP2F(x) __builtin_amdgcn_exp2f(x)
#else
#define EXP2F(x) exp2f(x)
#endif

__device__ inline unsigned short f2bf(float f) {   // RTNE
    unsigned u = __builtin_bit_cast(unsigned, f);
    u += 0x7fff + ((u >> 16) & 1);
    return (unsigned short)(u >> 16);
}
__device__ inline unsigned pack2(float a, float b) {
    return (unsigned)f2bf(a) | ((unsigned)f2bf(b) << 16);
}
__device__ inline unsigned pack2t(float a, float b) {  // truncation; for p >= 0
    unsigned ua = __builtin_bit_cast(unsigned, a);
    unsigned ub = __builtin_bit_cast(unsigned, b);
    return (ua >> 16) | (ub & 0xffff0000u);
}

// ---------------------------------------------------------------------------
// Kernel A: blocks 0..255: transpose x -> xT bf16 [b][n][c] (rows 256B).
//           block 256: convert W -> Wbf bf16 [160][128] (q rows *log2e), biasf.
// ---------------------------------------------------------------------------
__global__ __launch_bounds__(256) void prep_kernel(
    const float* __restrict__ x,
    const float* __restrict__ Wq, const float* __restrict__ bq,
    const float* __restrict__ Wk, const float* __restrict__ bk,
    const float* __restrict__ Wv, const float* __restrict__ bv,
    unsigned short* __restrict__ xT, unsigned short* __restrict__ Wbf,
    float* __restrict__ biasf)
{
    const int tid = threadIdx.x;
    if (blockIdx.x < 256) {
        const int b  = blockIdx.x >> 6;
        const int n  = ((blockIdx.x & 63) << 6) + (tid >> 2);
        const int c0 = (tid & 3) << 5;          // 32-channel chunk
        const float* xp = x + ((size_t)(b * Cn + c0)) * Nn + n;
        unsigned short* op = xT + ((size_t)b * Nn + n) * Cn + c0;
        unsigned w[16];
        #pragma unroll
        for (int i = 0; i < 16; ++i)
            w[i] = pack2(xp[(size_t)(2 * i) * Nn], xp[(size_t)(2 * i + 1) * Nn]);
        #pragma unroll
        for (int i = 0; i < 4; ++i)
            *reinterpret_cast<uint4*>(op + i * 8) =
                make_uint4(w[4 * i], w[4 * i + 1], w[4 * i + 2], w[4 * i + 3]);
    } else if (tid < 160) {
        const float LOG2E = 1.4426950408889634f;
        const float* src; float scale = 1.0f; float bias;
        if (tid < 16)      { src = Wq + tid * Cn;        scale = LOG2E; bias = bq[tid] * LOG2E; }
        else if (tid < 32) { src = Wk + (tid - 16) * Cn;                bias = bk[tid - 16]; }
        else               { src = Wv + (tid - 32) * Cn;                bias = bv[tid - 32]; }
        biasf[tid] = bias;
        unsigned* dst = reinterpret_cast<unsigned*>(Wbf + (size_t)tid * Cn);
        for (int c = 0; c < Cn; c += 2)
            dst[c >> 1] = pack2(src[c] * scale, src[c + 1] * scale);
    }
}

// ---------------------------------------------------------------------------
// Kernel B: qkv GEMM on MFMA. Block = 4 waves, n-tile 128 (32/wave).
// o-blocks: m=0 -> [q(16); k(16)], m=1..4 -> v channels 32(m-1)..
// A = xT rows (n), B = Wbf rows (o).  D[row=n][col=o].
// ---------------------------------------------------------------------------
__global__ __launch_bounds__(256) void qkv_kernel(
    const unsigned short* __restrict__ xT, const unsigned short* __restrict__ Wbf,
    const float* __restrict__ biasf,
    unsigned short* __restrict__ qT, unsigned short* __restrict__ kT,
    unsigned short* __restrict__ vv)
{
    __shared__ float qk_s[32][129];
    const int tid = threadIdx.x, wv = tid >> 6, lane = tid & 63;
    const int col = lane & 31, half = lane >> 5;
    const int b = blockIdx.x >> 5, n0 = (blockIdx.x & 31) << 7;
    const int nb = n0 + (wv << 5);

    bf16x8 af[8];
    const unsigned short* xrow = xT + ((size_t)b * Nn + nb + col) * Cn + 8 * half;
    #pragma unroll
    for (int s = 0; s < 8; ++s)
        af[s] = *reinterpret_cast<const bf16x8*>(xrow + 16 * s);

    for (int m = 0; m < 5; ++m) {
        const float binit = biasf[32 * m + col];
        f32x16 acc;
        #pragma unroll
        for (int r = 0; r < 16; ++r) acc[r] = binit;
        const unsigned short* wrow = Wbf + (size_t)(32 * m + col) * Cn + 8 * half;
        #pragma unroll
        for (int s = 0; s < 8; ++s) {
            bf16x8 bfr = *reinterpret_cast<const bf16x8*>(wrow + 16 * s);
            acc = __builtin_amdgcn_mfma_f32_32x32x16_bf16(af[s], bfr, acc, 0, 0, 0);
        }
        if (m == 0) {
            #pragma unroll
            for (int r = 0; r < 16; ++r)
                qk_s[col][(wv << 5) + (r & 3) + 8 * (r >> 2) + 4 * half] = acc[r];
        } else {
            const int c = 32 * (m - 1) + col;
            unsigned short* vp = vv + ((size_t)(b * Cn + c)) * Nn + nb + 4 * half;
            #pragma unroll
            for (int g = 0; g < 4; ++g)
                *reinterpret_cast<uint2*>(vp + 8 * g) =
                    make_uint2(pack2(acc[4 * g], acc[4 * g + 1]),
                               pack2(acc[4 * g + 2], acc[4 * g + 3]));
        }
    }
    __syncthreads();
    {   // qk_s [o][n] -> qT/kT [n][16] coalesced 32B rows
        const int n = tid & 127, which = tid >> 7;
        unsigned w[8];
        #pragma unroll
        for (int i = 0; i < 8; ++i)
            w[i] = pack2(qk_s[16 * which + 2 * i][n], qk_s[16 * which + 2 * i + 1][n]);
        unsigned short* dst = (which ? kT : qT) + ((size_t)b * Nn + n0 + n) * C8n;
        *reinterpret_cast<uint4*>(dst)     = make_uint4(w[0], w[1], w[2], w[3]);
        *reinterpret_cast<uint4*>(dst + 8) = make_uint4(w[4], w[5], w[6], w[7]);
    }
}

// ---------------------------------------------------------------------------
// Kernel C: attention, no-max softmax (q pre-scaled by log2e -> p = exp2(s)).
// Block = 8 waves; wave w: keys [512w, 512w+512), 16 iters of 32.
// Linear merge tree (sums only), distributed coalesced writeback.
// ---------------------------------------------------------------------------
__global__ __launch_bounds__(512) void attn_kernel(
    const unsigned short* __restrict__ qT, const unsigned short* __restrict__ kT,
    const unsigned short* __restrict__ vv, const float* __restrict__ x,
    const float* __restrict__ gamma_p, float* __restrict__ out)
{
    __shared__ float slot[2][4][16][64];
    __shared__ float ls[2][64];
    __shared__ float invl[32];

    const int tid = threadIdx.x, wv = tid >> 6, lane = tid & 63;
    const int col = lane & 31, half = lane >> 5;
    // XCD-chunked mapping: 2 XCDs per batch -> K/V L2-resident per XCD
    const int xcd = blockIdx.x & 7, sl = blockIdx.x >> 3;
    const int b = xcd >> 1;
    const int q0 = (sl + ((xcd & 1) << 6)) << 5;

    bf16x8 qf = *reinterpret_cast<const bf16x8*>(
        &qT[((size_t)b * Nn + q0 + col) * C8n + 8 * half]);

    f32x16 acc0 = {}, acc1 = {}, acc2 = {}, acc3 = {};
    float l_lane = 0.0f;
    const unsigned short* kb = kT + (size_t)b * Nn * C8n;
    const unsigned short* vb = vv + (size_t)b * Cn * Nn;

    for (int kt = 0; kt < 16; ++kt) {
        const int j0 = (wv << 9) + (kt << 5);
        bf16x8 kf = *reinterpret_cast<const bf16x8*>(
            &kb[(size_t)(j0 + col) * C8n + 8 * half]);
        f32x16 zz = {};
        f32x16 s = __builtin_amdgcn_mfma_f32_32x32x16_bf16(kf, qf, zz, 0, 0, 0);

        float p[16];
        #pragma unroll
        for (int r = 0; r < 16; ++r) p[r] = EXP2F(s[r]);
        float psum = 0.0f;
        #pragma unroll
        for (int r = 0; r < 16; ++r) psum += p[r];
        l_lane += psum;

        bf16x8 pf0, pf1;
        {
            unsigned lo0 = pack2t(p[0], p[1]), lo1 = pack2t(p[2], p[3]);
            unsigned hi0 = pack2t(p[4], p[5]), hi1 = pack2t(p[6], p[7]);
            unsigned s0 = half ? lo0 : hi0, s1 = half ? lo1 : hi1;
            unsigned r0 = (unsigned)__shfl_xor((int)s0, 32);
            unsigned r1 = (unsigned)__shfl_xor((int)s1, 32);
            uint4 u = make_uint4(half ? r0 : lo0, half ? r1 : lo1,
                                 half ? hi0 : r0, half ? hi1 : r1);
            pf0 = __builtin_bit_cast(bf16x8, u);
        }
        {
            unsigned lo0 = pack2t(p[8], p[9]),   lo1 = pack2t(p[10], p[11]);
            unsigned hi0 = pack2t(p[12], p[13]), hi1 = pack2t(p[14], p[15]);
            unsigned s0 = half ? lo0 : hi0, s1 = half ? lo1 : hi1;
            unsigned r0 = (unsigned)__shfl_xor((int)s0, 32);
            unsigned r1 = (unsigned)__shfl_xor((int)s1, 32);
            uint4 u = make_uint4(half ? r0 : lo0, half ? r1 : lo1,
                                 half ? hi0 : r0, half ? hi1 : r1);
            pf1 = __builtin_bit_cast(bf16x8, u);
        }

        const unsigned short* vt = vb + j0 + 8 * half;
        #define PVSTEP(CT, ACC) { \
            const unsigned short* vr = vt + (size_t)(32 * CT + col) * Nn; \
            bf16x8 va  = *reinterpret_cast<const bf16x8*>(vr); \
            bf16x8 vbb = *reinterpret_cast<const bf16x8*>(vr + 16); \
            ACC = __builtin_amdgcn_mfma_f32_32x32x16_bf16(va,  pf0, ACC, 0, 0, 0); \
            ACC = __builtin_amdgcn_mfma_f32_32x32x16_bf16(vbb, pf1, ACC, 0, 0, 0); }
        PVSTEP(0, acc0) PVSTEP(1, acc1) PVSTEP(2, acc2) PVSTEP(3, acc3)
        #undef PVSTEP
    }
    l_lane += __shfl_xor(l_lane, 32);   // both halves now hold this wave's full l

    // ---- linear merge: 8 waves -> wave 0 (sums only, no max logic) ----
    #define STORE_SLOT(SL) { \
        ls[SL][lane] = l_lane; \
        _Pragma("unroll") for (int r = 0; r < 16; ++r) { \
            slot[SL][0][r][lane] = acc0[r]; slot[SL][1][r][lane] = acc1[r]; \
            slot[SL][2][r][lane] = acc2[r]; slot[SL][3][r][lane] = acc3[r]; } }
    #define ADD_SLOT(SL) { \
        l_lane += ls[SL][lane]; \
        _Pragma("unroll") for (int r = 0; r < 16; ++r) { \
            acc0[r] += slot[SL][0][r][lane]; acc1[r] += slot[SL][1][r][lane]; \
            acc2[r] += slot[SL][2][r][lane]; acc3[r] += slot[SL][3][r][lane]; } }
    #define RMW_SLOT(SL) { \
        ls[SL][lane] += l_lane; \
        _Pragma("unroll") for (int r = 0; r < 16; ++r) { \
            slot[SL][0][r][lane] += acc0[r]; slot[SL][1][r][lane] += acc1[r]; \
            slot[SL][2][r][lane] += acc2[r]; slot[SL][3][r][lane] += acc3[r]; } }

    if (wv == 4 || wv == 5) STORE_SLOT(wv - 4);
    __syncthreads();
    if (wv == 0 || wv == 1) ADD_SLOT(wv);
    __syncthreads();
    if (wv == 6 || wv == 7) STORE_SLOT(wv - 6);
    __syncthreads();
    if (wv == 2 || wv == 3) RMW_SLOT(wv - 2);   // slot += own acc (owns the slot)
    __syncthreads();
    if (wv == 0 || wv == 1) ADD_SLOT(wv);
    __syncthreads();
    if (wv == 1) STORE_SLOT(0);
    __syncthreads();
    if (wv == 0) {
        ADD_SLOT(0);
        STORE_SLOT(0);                          // stage final acc for writeback
        if (lane < 32) invl[lane] = 1.0f / l_lane;
    }
    __syncthreads();
    #undef STORE_SLOT
    #undef ADD_SLOT
    #undef RMW_SLOT

    // ---- distributed coalesced writeback: 8 passes x 512 thr = 4096 elems ----
    {
        const float g = gamma_p[0];
        const int n = tid & 31, ci = tid >> 5;      // ci 0..15
        const float il = invl[n];
        #pragma unroll
        for (int pass = 0; pass < 8; ++pass) {
            int c  = ci + (pass << 4);
            int ct = c >> 5, cl = c & 31;
            int r  = (cl & 3) + ((cl >> 3) << 2);
            int lp = n + ((cl >> 2) & 1) * 32;
            float val = slot[0][ct][r][lp];
            size_t idx = ((size_t)(b * Cn + c)) * Nn + q0 + n;
            out[idx] = g * (val * il) + x[idx];
        }
    }
}

// ---------------------------------------------------------------------------
extern "C" void kernel_launch(void* const* d_in, const int* in_sizes, int n_in,
                              void* d_out, int out_size, void* d_ws, size_t ws_size,
                              hipStream_t stream)
{
    const float* x     = (const float*)d_in[0];
    const float* Wq    = (const float*)d_in[1];
    const float* bq    = (const float*)d_in[2];
    const float* Wk    = (const float*)d_in[3];
    const float* bk    = (const float*)d_in[4];
    const float* Wv    = (const float*)d_in[5];
    const float* bv    = (const float*)d_in[6];
    const float* gamma = (const float*)d_in[7];
    float* out = (float*)d_out;

    // ws (elements of u16): qT | kT | vv | xT | Wbf, then biasf (f32)
    unsigned short* ws16 = (unsigned short*)d_ws;
    unsigned short* qTw  = ws16;                                  // 262144
    unsigned short* kTw  = qTw + (size_t)Bn * Nn * C8n;           // 262144
    unsigned short* vw   = kTw + (size_t)Bn * Nn * C8n;           // 2097152
    unsigned short* xTw  = vw  + (size_t)Bn * Cn * Nn;            // 2097152
    unsigned short* Wbfw = xTw + (size_t)Bn * Nn * Cn;            // 20480
    float* biasfw = (float*)(Wbfw + 160 * Cn);                    // 160 f32

    prep_kernel<<<dim3(257), dim3(256), 0, stream>>>(
        x, Wq, bq, Wk, bk, Wv, bv, xTw, Wbfw, biasfw);

    qkv_kernel<<<dim3(128), dim3(256), 0, stream>>>(
        xTw, Wbfw, biasfw, qTw, kTw, vw);

    attn_kernel<<<dim3(512), dim3(512), 0, stream>>>(
        qTw, kTw, vw, x, gamma, out);
}

// Round 5
// 114.067 us; speedup vs baseline: 6.7223x; 1.3761x over previous
//
#include <hip/hip_runtime.h>
#include <math.h>

typedef __attribute__((ext_vector_type(8))) short bf16x8;
typedef __attribute__((ext_vector_type(16))) float f32x16;

constexpr int Bn = 4, Cn = 128, C8n = 16, Nn = 4096;

#if __has_builtin(__builtin_amdgcn_exp2f)
#define EXP2F(x) __builtin_amdgcn_exp2f(x)
#else
#define EXP2F(x) exp2f(x)
#endif

__device__ inline unsigned short f2bf(float f) {   // RTNE
    unsigned u = __builtin_bit_cast(unsigned, f);
    u += 0x7fff + ((u >> 16) & 1);
    return (unsigned short)(u >> 16);
}
__device__ inline unsigned pack2(float a, float b) {
    return (unsigned)f2bf(a) | ((unsigned)f2bf(b) << 16);
}
__device__ inline unsigned pkt(float a, float b) {  // truncating pack: lo=a, hi=b
#if __has_builtin(__builtin_amdgcn_perm)
    return __builtin_amdgcn_perm(__builtin_bit_cast(unsigned, b),
                                 __builtin_bit_cast(unsigned, a), 0x07060302u);
#else
    return (__builtin_bit_cast(unsigned, a) >> 16) |
           (__builtin_bit_cast(unsigned, b) & 0xffff0000u);
#endif
}

// ---------------------------------------------------------------------------
// Kernel 1: fused qkv projection GEMM (MFMA), reads x directly.
// Outputs: qT/kT [b][n][16] bf16 (frag-ready rows, q pre-scaled by log2e),
//          vsw   [b][n/16][ct][lane] bf16x8  (exact PV A-fragment order).
// Block: 256 thr = 4 waves; n-tile 64 (2 n-subs x 2 m-sets).
// ---------------------------------------------------------------------------
__global__ __launch_bounds__(256) void qkv_kernel(
    const float* __restrict__ x,
    const float* __restrict__ Wq, const float* __restrict__ bq,
    const float* __restrict__ Wk, const float* __restrict__ bk,
    const float* __restrict__ Wv, const float* __restrict__ bv,
    unsigned short* __restrict__ qT, unsigned short* __restrict__ kT,
    unsigned short* __restrict__ vsw)
{
    __shared__ unsigned short wlds[160 * 128];   // W bf16, XOR-swizzled rows
    __shared__ unsigned short v_s[32 * 128];     // v transpose buffer, swizzled
    __shared__ float qk_s[32][65];
    __shared__ float bfl[160];

    const int tid = threadIdx.x;
    const int b = blockIdx.x >> 6, n0 = (blockIdx.x & 63) << 6;
    const int w = tid >> 6, lane = tid & 63, col = lane & 31, half = lane >> 5;
    const float L2E = 1.4426950408889634f;

    // ---- stage W -> LDS (bf16, q rows scaled; XOR-swizzled 8-elem groups) ----
    {
        unsigned* wl32 = (unsigned*)wlds;
        for (int i = tid; i < 160 * 32; i += 256) {
            int r = i >> 5, cq = (i & 31) << 2;
            const float* src; float sc = 1.0f;
            if (r < 16)      { src = Wq + (size_t)r * Cn;        sc = L2E; }
            else if (r < 32) { src = Wk + (size_t)(r - 16) * Cn; }
            else             { src = Wv + (size_t)(r - 32) * Cn; }
            float4 t = *reinterpret_cast<const float4*>(&src[cq]);
            int G = cq >> 3;
            unsigned* wp = wl32 + 64 * r + 4 * (G ^ (r & 7)) + ((cq & 7) >> 1);
            wp[0] = pack2(t.x * sc, t.y * sc);
            wp[1] = pack2(t.z * sc, t.w * sc);
        }
        if (tid < 160)
            bfl[tid] = (tid < 16) ? bq[tid] * L2E
                     : (tid < 32) ? bk[tid - 16] : bv[tid - 32];
    }

    // ---- A-frags: direct from x, coalesced rows, pack to bf16 ----
    const int nx = n0 + ((w & 1) << 5);
    const float* xb = x + ((size_t)b * Cn) * Nn + nx + col;
    bf16x8 af[8];
    #pragma unroll
    for (int s = 0; s < 8; ++s) {
        float v[8];
        #pragma unroll
        for (int j = 0; j < 8; ++j)
            v[j] = xb[(size_t)(16 * s + 8 * half + j) * Nn];
        uint4 u = make_uint4(pack2(v[0], v[1]), pack2(v[2], v[3]),
                             pack2(v[4], v[5]), pack2(v[6], v[7]));
        af[s] = __builtin_bit_cast(bf16x8, u);
    }
    __syncthreads();

    // ---- MFMA: wave's m-set ({qk,v0,v1} or {v2,v3}) ----
    const int mb = (w >> 1) ? 3 : 0;
    const bool three = (w >> 1) == 0;
    f32x16 a0, a1, a2;
    {
        float b0 = bfl[32 * mb + col], b1 = bfl[32 * (mb + 1) + col];
        float b2v = three ? bfl[64 + col] : 0.0f;
        #pragma unroll
        for (int r = 0; r < 16; ++r) { a0[r] = b0; a1[r] = b1; a2[r] = b2v; }
    }
    #pragma unroll
    for (int s = 0; s < 8; ++s) {
        const int off = 8 * ((2 * s + half) ^ (col & 7));
        a0 = __builtin_amdgcn_mfma_f32_32x32x16_bf16(af[s],
             *(const bf16x8*)(wlds + 128 * (32 * mb + col) + off), a0, 0, 0, 0);
        a1 = __builtin_amdgcn_mfma_f32_32x32x16_bf16(af[s],
             *(const bf16x8*)(wlds + 128 * (32 * (mb + 1) + col) + off), a1, 0, 0, 0);
        if (three)
            a2 = __builtin_amdgcn_mfma_f32_32x32x16_bf16(af[s],
                 *(const bf16x8*)(wlds + 128 * (64 + col) + off), a2, 0, 0, 0);
    }

    // v_s write: [ch 32][n 64] bf16, XOR-swizzled groups, RTNE
    unsigned* vp32 = (unsigned*)v_s;
    #define VS_WRITE(A) { \
        _Pragma("unroll") for (int g = 0; g < 4; ++g) { \
            int n_ = ((w & 1) << 5) + (g << 3) + (half << 2); \
            int Gn = n_ >> 3; \
            int u_ = 64 * col + 4 * (Gn ^ (col & 7)) + (half << 1); \
            vp32[u_]     = pack2(A[4 * g],     A[4 * g + 1]); \
            vp32[u_ + 1] = pack2(A[4 * g + 2], A[4 * g + 3]); } }

    // v_s -> global vsw in fragment order (coalesced uint4)
    #define VS_OUT(CT) { \
        int c_ = lane & 31, Gt = ((tid >> 6) << 1) + (lane >> 5); \
        bf16x8 fr = *(const bf16x8*)&v_s[128 * c_ + 8 * (Gt ^ (c_ & 7))]; \
        size_t o_ = ((((size_t)b * 256 + (n0 >> 4) + (tid >> 6)) * 4 + (CT)) * 64 + lane) * 8; \
        *reinterpret_cast<uint4*>(&vsw[o_]) = __builtin_bit_cast(uint4, fr); }

    // phase 1: qk (waves 0,1) + v ct2 (waves 2,3, m=3)
    if (w < 2) {
        #pragma unroll
        for (int r = 0; r < 16; ++r)
            qk_s[col][((w & 1) << 5) + (r & 3) + ((r >> 2) << 3) + (half << 2)] = a0[r];
    } else {
        VS_WRITE(a0)
    }
    __syncthreads();
    VS_OUT(2)
    if (tid < 128) {
        int n = tid & 63, which = tid >> 6;
        unsigned wv_[8];
        #pragma unroll
        for (int i = 0; i < 8; ++i)
            wv_[i] = pack2(qk_s[16 * which + 2 * i][n], qk_s[16 * which + 2 * i + 1][n]);
        unsigned short* dst = (which ? kT : qT) + ((size_t)b * Nn + n0 + n) * C8n;
        *reinterpret_cast<uint4*>(dst)     = make_uint4(wv_[0], wv_[1], wv_[2], wv_[3]);
        *reinterpret_cast<uint4*>(dst + 8) = make_uint4(wv_[4], wv_[5], wv_[6], wv_[7]);
    }
    __syncthreads();
    if (w < 2) VS_WRITE(a1)            // m=1 -> ct0
    __syncthreads();
    VS_OUT(0)
    __syncthreads();
    if (w >= 2) VS_WRITE(a1)           // m=4 -> ct3
    __syncthreads();
    VS_OUT(3)
    __syncthreads();
    if (w < 2) VS_WRITE(a2)            // m=2 -> ct1
    __syncthreads();
    VS_OUT(1)
    #undef VS_WRITE
    #undef VS_OUT
}

// ---------------------------------------------------------------------------
// Kernel 2: attention. Block = 8 waves, 64 queries (2 q-subs), 8-way key split.
// No-max softmax (q pre-scaled by log2e): p = exp2(s). V loads fully coalesced
// from the swizzled fragment layout. bf16-packed LDS merge (2 slots).
// NOTE: no min-waves bound — live state ~240 VGPR; capping at 128 would spill.
// ---------------------------------------------------------------------------
__global__ __launch_bounds__(512) void attn_kernel(
    const unsigned short* __restrict__ qT, const unsigned short* __restrict__ kT,
    const unsigned short* __restrict__ vsw, const float* __restrict__ x,
    const float* __restrict__ gamma_p, float* __restrict__ out)
{
    __shared__ unsigned sm_u32[8192];          // 32 KB: 2 bf16 slots / final f32
    __shared__ float ls[2][2][64];
    __shared__ float invl[64];

    const int tid = threadIdx.x, wv = tid >> 6, lane = tid & 63;
    const int col = lane & 31, half = lane >> 5;
    // XCD-chunked: batch b owns XCDs {2b, 2b+1}
    const int xcd = blockIdx.x & 7;
    const int b = xcd >> 1;
    const int q0 = ((((blockIdx.x >> 3) << 1) | (xcd & 1))) << 6;

    const unsigned short* qb = qT + (size_t)b * Nn * C8n;
    bf16x8 qf0 = *(const bf16x8*)&qb[(size_t)(q0 + col) * C8n + 8 * half];
    bf16x8 qf1 = *(const bf16x8*)&qb[(size_t)(q0 + 32 + col) * C8n + 8 * half];

    f32x16 accA[4], accB[4];
    #pragma unroll
    for (int ct = 0; ct < 4; ++ct) { accA[ct] = {}; accB[ct] = {}; }
    float l0 = 0.0f, l1 = 0.0f;
    const unsigned short* kb = kT + (size_t)b * Nn * C8n;

    for (int kt = 0; kt < 16; ++kt) {
        const int j0 = (wv << 9) + (kt << 5);
        // V fragments: lane-contiguous loads (2 key-16-tiles x 4 ct)
        const size_t vbase = ((((size_t)b * 256 + (j0 >> 4)) * 4) * 64 + lane) * 8;
        bf16x8 va[4], vb2[4];
        #pragma unroll
        for (int ct = 0; ct < 4; ++ct) {
            va[ct]  = *(const bf16x8*)&vsw[vbase + (size_t)ct * 512];
            vb2[ct] = *(const bf16x8*)&vsw[vbase + (size_t)(4 + ct) * 512];
        }
        bf16x8 kf = *(const bf16x8*)&kb[(size_t)(j0 + col) * C8n + 8 * half];
        f32x16 z = {};
        f32x16 s0 = __builtin_amdgcn_mfma_f32_32x32x16_bf16(kf, qf0, z, 0, 0, 0);
        f32x16 s1 = __builtin_amdgcn_mfma_f32_32x32x16_bf16(kf, qf1, z, 0, 0, 0);

        float p0[16], p1[16];
        float ps0 = 0.0f, ps1 = 0.0f;
        #pragma unroll
        for (int r = 0; r < 16; ++r) { p0[r] = EXP2F(s0[r]); ps0 += p0[r]; }
        #pragma unroll
        for (int r = 0; r < 16; ++r) { p1[r] = EXP2F(s1[r]); ps1 += p1[r]; }
        ps0 += __shfl_xor(ps0, 32); l0 += ps0;
        ps1 += __shfl_xor(ps1, 32); l1 += ps1;

        // build P B-frags (truncating pack + cross-half exchange)
        #define MKPF(P, O, F) { \
            unsigned lo0 = pkt(P[O], P[O + 1]), lo1 = pkt(P[O + 2], P[O + 3]); \
            unsigned hi0 = pkt(P[O + 4], P[O + 5]), hi1 = pkt(P[O + 6], P[O + 7]); \
            unsigned t0 = half ? lo0 : hi0, t1 = half ? lo1 : hi1; \
            unsigned r0 = (unsigned)__shfl_xor((int)t0, 32); \
            unsigned r1 = (unsigned)__shfl_xor((int)t1, 32); \
            uint4 u_ = make_uint4(half ? r0 : lo0, half ? r1 : lo1, \
                                  half ? hi0 : r0, half ? hi1 : r1); \
            F = __builtin_bit_cast(bf16x8, u_); }
        bf16x8 pa0, pa1, pb0, pb1;
        MKPF(p0, 0, pa0) MKPF(p0, 8, pa1)
        MKPF(p1, 0, pb0) MKPF(p1, 8, pb1)
        #undef MKPF

        #pragma unroll
        for (int ct = 0; ct < 4; ++ct) {
            accA[ct] = __builtin_amdgcn_mfma_f32_32x32x16_bf16(va[ct],  pa0, accA[ct], 0, 0, 0);
            accA[ct] = __builtin_amdgcn_mfma_f32_32x32x16_bf16(vb2[ct], pa1, accA[ct], 0, 0, 0);
            accB[ct] = __builtin_amdgcn_mfma_f32_32x32x16_bf16(va[ct],  pb0, accB[ct], 0, 0, 0);
            accB[ct] = __builtin_amdgcn_mfma_f32_32x32x16_bf16(vb2[ct], pb1, accB[ct], 0, 0, 0);
        }
    }

    // ---- 8-wave merge, bf16-packed slots ----
    #define SL_STORE(SL) { \
        ls[SL][0][lane] = l0; ls[SL][1][lane] = l1; \
        unsigned* sb = sm_u32 + (SL) * 4096; \
        _Pragma("unroll") for (int ct = 0; ct < 4; ++ct) \
        _Pragma("unroll") for (int i = 0; i < 8; ++i) { \
            sb[((ct) * 8 + i) * 64 + lane]     = pkt(accA[ct][2 * i], accA[ct][2 * i + 1]); \
            sb[((4 + ct) * 8 + i) * 64 + lane] = pkt(accB[ct][2 * i], accB[ct][2 * i + 1]); } }
    #define SL_ADD(SL) { \
        l0 += ls[SL][0][lane]; l1 += ls[SL][1][lane]; \
        unsigned* sb = sm_u32 + (SL) * 4096; \
        _Pragma("unroll") for (int ct = 0; ct < 4; ++ct) \
        _Pragma("unroll") for (int i = 0; i < 8; ++i) { \
            unsigned ua = sb[((ct) * 8 + i) * 64 + lane]; \
            accA[ct][2 * i]     += __builtin_bit_cast(float, ua << 16); \
            accA[ct][2 * i + 1] += __builtin_bit_cast(float, ua & 0xffff0000u); \
            unsigned ub = sb[((4 + ct) * 8 + i) * 64 + lane]; \
            accB[ct][2 * i]     += __builtin_bit_cast(float, ub << 16); \
            accB[ct][2 * i + 1] += __builtin_bit_cast(float, ub & 0xffff0000u); } }
    #define SL_RMW(SL) { \
        ls[SL][0][lane] += l0; ls[SL][1][lane] += l1; \
        unsigned* sb = sm_u32 + (SL) * 4096; \
        _Pragma("unroll") for (int ct = 0; ct < 4; ++ct) \
        _Pragma("unroll") for (int i = 0; i < 8; ++i) { \
            unsigned ua = sb[((ct) * 8 + i) * 64 + lane]; \
            float x0 = __builtin_bit_cast(float, ua << 16) + accA[ct][2 * i]; \
            float x1 = __builtin_bit_cast(float, ua & 0xffff0000u) + accA[ct][2 * i + 1]; \
            sb[((ct) * 8 + i) * 64 + lane] = pkt(x0, x1); \
            unsigned ub = sb[((4 + ct) * 8 + i) * 64 + lane]; \
            float y0 = __builtin_bit_cast(float, ub << 16) + accB[ct][2 * i]; \
            float y1 = __builtin_bit_cast(float, ub & 0xffff0000u) + accB[ct][2 * i + 1]; \
            sb[((4 + ct) * 8 + i) * 64 + lane] = pkt(y0, y1); } }

    if (wv == 4 || wv == 5) SL_STORE(wv - 4)
    __syncthreads();
    if (wv == 0 || wv == 1) SL_ADD(wv)
    __syncthreads();
    if (wv == 6 || wv == 7) SL_STORE(wv - 6)
    __syncthreads();
    if (wv == 2 || wv == 3) SL_RMW(wv - 2)
    __syncthreads();
    if (wv == 0 || wv == 1) SL_ADD(wv)
    __syncthreads();
    if (wv == 1) SL_STORE(0)
    __syncthreads();
    float* sf = (float*)sm_u32;
    if (wv == 0) {
        SL_ADD(0)
        #pragma unroll
        for (int ct = 0; ct < 4; ++ct)
            #pragma unroll
            for (int r = 0; r < 16; ++r) {
                sf[((ct) * 16 + r) * 64 + lane]     = accA[ct][r];
                sf[((4 + ct) * 16 + r) * 64 + lane] = accB[ct][r];
            }
        if (lane < 32) { invl[col] = 1.0f / l0; invl[32 + col] = 1.0f / l1; }
    }
    __syncthreads();
    #undef SL_STORE
    #undef SL_ADD
    #undef SL_RMW

    // ---- distributed coalesced writeback: 16 passes x 512 thr ----
    {
        const float g = gamma_p[0];
        const int n = tid & 63, ci = tid >> 6;
        const float il = invl[n];
        const int qs = n >> 5, nc = n & 31;
        #pragma unroll
        for (int p = 0; p < 16; ++p) {
            int ch = (p << 3) + ci;
            int ct = ch >> 5, chl = ch & 31;
            int h = (chl >> 2) & 1, r = (chl & 3) | ((chl >> 3) << 2);
            float val = sf[((qs * 4 + ct) * 16 + r) * 64 + nc + (h << 5)];
            size_t idx = ((size_t)(b * Cn + ch)) * Nn + q0 + n;
            out[idx] = g * (val * il) + x[idx];
        }
    }
}

// ---------------------------------------------------------------------------
extern "C" void kernel_launch(void* const* d_in, const int* in_sizes, int n_in,
                              void* d_out, int out_size, void* d_ws, size_t ws_size,
                              hipStream_t stream)
{
    const float* x     = (const float*)d_in[0];
    const float* Wq    = (const float*)d_in[1];
    const float* bq    = (const float*)d_in[2];
    const float* Wk    = (const float*)d_in[3];
    const float* bk    = (const float*)d_in[4];
    const float* Wv    = (const float*)d_in[5];
    const float* bv    = (const float*)d_in[6];
    const float* gamma = (const float*)d_in[7];
    float* out = (float*)d_out;

    unsigned short* ws16 = (unsigned short*)d_ws;
    unsigned short* qTw  = ws16;                              // 262144 u16
    unsigned short* kTw  = qTw + (size_t)Bn * Nn * C8n;       // 262144 u16
    unsigned short* vsww = kTw + (size_t)Bn * Nn * C8n;       // 2097152 u16

    qkv_kernel<<<dim3(256), dim3(256), 0, stream>>>(
        x, Wq, bq, Wk, bk, Wv, bv, qTw, kTw, vsww);

    attn_kernel<<<dim3(256), dim3(512), 0, stream>>>(
        qTw, kTw, vsww, x, gamma, out);
}

// Round 6
// 113.793 us; speedup vs baseline: 6.7385x; 1.0024x over previous
//
#include <hip/hip_runtime.h>
#include <math.h>

typedef __attribute__((ext_vector_type(8))) short bf16x8;
typedef __attribute__((ext_vector_type(16))) float f32x16;

constexpr int Bn = 4, Cn = 128, C8n = 16, Nn = 4096;

#if __has_builtin(__builtin_amdgcn_exp2f)
#define EXP2F(x) __builtin_amdgcn_exp2f(x)
#else
#define EXP2F(x) exp2f(x)
#endif

__device__ inline unsigned short f2bf(float f) {   // RTNE
    unsigned u = __builtin_bit_cast(unsigned, f);
    u += 0x7fff + ((u >> 16) & 1);
    return (unsigned short)(u >> 16);
}
__device__ inline unsigned pack2(float a, float b) {
    return (unsigned)f2bf(a) | ((unsigned)f2bf(b) << 16);
}
__device__ inline unsigned pkt(float a, float b) {  // truncating pack: lo=a, hi=b
#if __has_builtin(__builtin_amdgcn_perm)
    return __builtin_amdgcn_perm(__builtin_bit_cast(unsigned, b),
                                 __builtin_bit_cast(unsigned, a), 0x07060302u);
#else
    return (__builtin_bit_cast(unsigned, a) >> 16) |
           (__builtin_bit_cast(unsigned, b) & 0xffff0000u);
#endif
}

// ---------------------------------------------------------------------------
// Kernel 1: fused qkv projection GEMM (MFMA), reads x directly.
// Outputs: qT/kT [b][n][16] bf16 (frag-ready rows, q pre-scaled by log2e),
//          vsw   [b][n/16][ct][lane] bf16x8  (exact PV A-fragment order).
// Block: 256 thr = 4 waves; n-tile 64. 3 barriers total (was 9):
// all v channels go through one swizzled v_s[128][64], written once.
// ---------------------------------------------------------------------------
__global__ __launch_bounds__(256) void qkv_kernel(
    const float* __restrict__ x,
    const float* __restrict__ Wq, const float* __restrict__ bq,
    const float* __restrict__ Wk, const float* __restrict__ bk,
    const float* __restrict__ Wv, const float* __restrict__ bv,
    unsigned short* __restrict__ qT, unsigned short* __restrict__ kT,
    unsigned short* __restrict__ vsw)
{
    __shared__ unsigned short wlds[160 * 128];   // 40 KB: W bf16, swizzled rows
    __shared__ unsigned short v_s[128 * 64];     // 16 KB: [ch][n], swizzled
    __shared__ float qk_s[32][65];
    __shared__ float bfl[160];

    const int tid = threadIdx.x;
    const int b = blockIdx.x >> 6, n0 = (blockIdx.x & 63) << 6;
    const int w = tid >> 6, lane = tid & 63, col = lane & 31, half = lane >> 5;
    const float L2E = 1.4426950408889634f;

    // ---- stage W -> LDS (bf16, q rows scaled; XOR-swizzled 8-elem groups) ----
    {
        unsigned* wl32 = (unsigned*)wlds;
        for (int i = tid; i < 160 * 32; i += 256) {
            int r = i >> 5, cq = (i & 31) << 2;
            const float* src; float sc = 1.0f;
            if (r < 16)      { src = Wq + (size_t)r * Cn;        sc = L2E; }
            else if (r < 32) { src = Wk + (size_t)(r - 16) * Cn; }
            else             { src = Wv + (size_t)(r - 32) * Cn; }
            float4 t = *reinterpret_cast<const float4*>(&src[cq]);
            int G = cq >> 3;
            unsigned* wp = wl32 + 64 * r + 4 * (G ^ (r & 7)) + ((cq & 7) >> 1);
            wp[0] = pack2(t.x * sc, t.y * sc);
            wp[1] = pack2(t.z * sc, t.w * sc);
        }
        if (tid < 160)
            bfl[tid] = (tid < 16) ? bq[tid] * L2E
                     : (tid < 32) ? bk[tid - 16] : bv[tid - 32];
    }

    // ---- A-frags: direct from x, coalesced rows, pack to bf16 ----
    const int nx = n0 + ((w & 1) << 5);
    const float* xb = x + ((size_t)b * Cn) * Nn + nx + col;
    bf16x8 af[8];
    #pragma unroll
    for (int s = 0; s < 8; ++s) {
        float v[8];
        #pragma unroll
        for (int j = 0; j < 8; ++j)
            v[j] = xb[(size_t)(16 * s + 8 * half + j) * Nn];
        uint4 u = make_uint4(pack2(v[0], v[1]), pack2(v[2], v[3]),
                             pack2(v[4], v[5]), pack2(v[6], v[7]));
        af[s] = __builtin_bit_cast(bf16x8, u);
    }
    __syncthreads();                                        // barrier 1

    // ---- MFMA: w0/w1 -> m {0=qk,1,2}; w2/w3 -> m {3,4} ----
    const int mb = (w >> 1) ? 3 : 0;
    const bool three = (w >> 1) == 0;
    f32x16 a0, a1, a2;
    {
        float b0 = bfl[32 * mb + col], b1 = bfl[32 * (mb + 1) + col];
        float b2v = three ? bfl[64 + col] : 0.0f;
        #pragma unroll
        for (int r = 0; r < 16; ++r) { a0[r] = b0; a1[r] = b1; a2[r] = b2v; }
    }
    #pragma unroll
    for (int s = 0; s < 8; ++s) {
        const int off = 8 * ((2 * s + half) ^ (col & 7));
        a0 = __builtin_amdgcn_mfma_f32_32x32x16_bf16(af[s],
             *(const bf16x8*)(wlds + 128 * (32 * mb + col) + off), a0, 0, 0, 0);
        a1 = __builtin_amdgcn_mfma_f32_32x32x16_bf16(af[s],
             *(const bf16x8*)(wlds + 128 * (32 * (mb + 1) + col) + off), a1, 0, 0, 0);
        if (three)
            a2 = __builtin_amdgcn_mfma_f32_32x32x16_bf16(af[s],
                 *(const bf16x8*)(wlds + 128 * (64 + col) + off), a2, 0, 0, 0);
    }

    // ---- single write phase: qk -> qk_s, all v -> v_s ----
    // v_s u32 layout: row c (0..127) = 32 u32; u32 idx = 32c + 4*(Gn^(c&7)) + w3
    // where Gn = n>>3, w3 = (n&7)>>1.
    unsigned* vp32 = (unsigned*)v_s;
    #define VS_WRITE(A, C0) { \
        const int c_ = (C0) + col; \
        _Pragma("unroll") for (int g = 0; g < 4; ++g) { \
            int Gn = ((w & 1) << 2) + g; \
            unsigned* up = vp32 + 32 * c_ + 4 * (Gn ^ (c_ & 7)) + (half << 1); \
            up[0] = pack2(A[4 * g],     A[4 * g + 1]); \
            up[1] = pack2(A[4 * g + 2], A[4 * g + 3]); } }

    if (w < 2) {
        #pragma unroll
        for (int r = 0; r < 16; ++r)
            qk_s[col][((w & 1) << 5) + (r & 3) + ((r >> 2) << 3) + (half << 2)] = a0[r];
        VS_WRITE(a1, 0)          // m=1 -> ch 0-31
        VS_WRITE(a2, 32)         // m=2 -> ch 32-63
    } else {
        VS_WRITE(a0, 64)         // m=3 -> ch 64-95
        VS_WRITE(a1, 96)         // m=4 -> ch 96-127
    }
    #undef VS_WRITE
    __syncthreads();                                        // barrier 2

    // ---- outputs: qk (128 thr) + v fragments (wave w -> ct=w, 4 tiles) ----
    if (tid < 128) {
        int n = tid & 63, which = tid >> 6;
        unsigned wv_[8];
        #pragma unroll
        for (int i = 0; i < 8; ++i)
            wv_[i] = pack2(qk_s[16 * which + 2 * i][n], qk_s[16 * which + 2 * i + 1][n]);
        unsigned short* dst = (which ? kT : qT) + ((size_t)b * Nn + n0 + n) * C8n;
        *reinterpret_cast<uint4*>(dst)     = make_uint4(wv_[0], wv_[1], wv_[2], wv_[3]);
        *reinterpret_cast<uint4*>(dst + 8) = make_uint4(wv_[4], wv_[5], wv_[6], wv_[7]);
    }
    {
        const int ct = w, c_ = (ct << 5) + col;
        #pragma unroll
        for (int t = 0; t < 4; ++t) {
            int Gn = (t << 1) + half;
            bf16x8 fr = *(const bf16x8*)(vp32 + 32 * c_ + 4 * (Gn ^ (c_ & 7)));
            size_t o_ = ((((size_t)b * 256 + (n0 >> 4) + t) * 4 + ct) * 64 + lane) * 8;
            *reinterpret_cast<uint4*>(&vsw[o_]) = __builtin_bit_cast(uint4, fr);
        }
    }
}

// ---------------------------------------------------------------------------
// Kernel 2: attention. Block = 8 waves, 64 queries (2 q-subs), 8-way key split.
// No-max softmax (q pre-scaled by log2e): p = exp2(s). V loads fully coalesced.
// Inner loop processes q-sub A completely before q-sub B -> peak live VGPRs
// ~200 (R5's interleaved version exceeded the 256 cap -> scratch spills).
// ---------------------------------------------------------------------------
__global__ __launch_bounds__(512) void attn_kernel(
    const unsigned short* __restrict__ qT, const unsigned short* __restrict__ kT,
    const unsigned short* __restrict__ vsw, const float* __restrict__ x,
    const float* __restrict__ gamma_p, float* __restrict__ out)
{
    __shared__ unsigned sm_u32[8192];          // 32 KB: 2 bf16 slots / final f32
    __shared__ float ls[2][2][64];
    __shared__ float invl[64];

    const int tid = threadIdx.x, wv = tid >> 6, lane = tid & 63;
    const int col = lane & 31, half = lane >> 5;
    // XCD-chunked: batch b owns XCDs {2b, 2b+1}
    const int xcd = blockIdx.x & 7;
    const int b = xcd >> 1;
    const int q0 = ((((blockIdx.x >> 3) << 1) | (xcd & 1))) << 6;

    const unsigned short* qb = qT + (size_t)b * Nn * C8n;
    bf16x8 qf0 = *(const bf16x8*)&qb[(size_t)(q0 + col) * C8n + 8 * half];
    bf16x8 qf1 = *(const bf16x8*)&qb[(size_t)(q0 + 32 + col) * C8n + 8 * half];

    f32x16 accA[4], accB[4];
    #pragma unroll
    for (int ct = 0; ct < 4; ++ct) { accA[ct] = {}; accB[ct] = {}; }
    float l0 = 0.0f, l1 = 0.0f;
    const unsigned short* kb = kT + (size_t)b * Nn * C8n;

    // build P B-frags (truncating pack + cross-half exchange)
    #define MKPF(P, O, F) { \
        unsigned lo0 = pkt(P[O], P[O + 1]), lo1 = pkt(P[O + 2], P[O + 3]); \
        unsigned hi0 = pkt(P[O + 4], P[O + 5]), hi1 = pkt(P[O + 6], P[O + 7]); \
        unsigned t0 = half ? lo0 : hi0, t1 = half ? lo1 : hi1; \
        unsigned r0 = (unsigned)__shfl_xor((int)t0, 32); \
        unsigned r1 = (unsigned)__shfl_xor((int)t1, 32); \
        uint4 u_ = make_uint4(half ? r0 : lo0, half ? r1 : lo1, \
                              half ? hi0 : r0, half ? hi1 : r1); \
        F = __builtin_bit_cast(bf16x8, u_); }

    #pragma unroll 1
    for (int kt = 0; kt < 16; ++kt) {
        const int j0 = (wv << 9) + (kt << 5);
        const size_t vbase = ((((size_t)b * 256 + (j0 >> 4)) * 4) * 64 + lane) * 8;
        bf16x8 va[4], vb2[4];
        #pragma unroll
        for (int ct = 0; ct < 4; ++ct) {
            va[ct]  = *(const bf16x8*)&vsw[vbase + (size_t)ct * 512];
            vb2[ct] = *(const bf16x8*)&vsw[vbase + (size_t)(4 + ct) * 512];
        }
        bf16x8 kf = *(const bf16x8*)&kb[(size_t)(j0 + col) * C8n + 8 * half];
        f32x16 z = {};

        // ---- q-sub A: scores -> p -> frags -> PV ----
        {
            f32x16 s = __builtin_amdgcn_mfma_f32_32x32x16_bf16(kf, qf0, z, 0, 0, 0);
            float p[16]; float ps = 0.0f;
            #pragma unroll
            for (int r = 0; r < 16; ++r) { p[r] = EXP2F(s[r]); ps += p[r]; }
            ps += __shfl_xor(ps, 32); l0 += ps;
            bf16x8 pf0, pf1;
            MKPF(p, 0, pf0) MKPF(p, 8, pf1)
            #pragma unroll
            for (int ct = 0; ct < 4; ++ct) {
                accA[ct] = __builtin_amdgcn_mfma_f32_32x32x16_bf16(va[ct],  pf0, accA[ct], 0, 0, 0);
                accA[ct] = __builtin_amdgcn_mfma_f32_32x32x16_bf16(vb2[ct], pf1, accA[ct], 0, 0, 0);
            }
        }
        // ---- q-sub B ----
        {
            f32x16 s = __builtin_amdgcn_mfma_f32_32x32x16_bf16(kf, qf1, z, 0, 0, 0);
            float p[16]; float ps = 0.0f;
            #pragma unroll
            for (int r = 0; r < 16; ++r) { p[r] = EXP2F(s[r]); ps += p[r]; }
            ps += __shfl_xor(ps, 32); l1 += ps;
            bf16x8 pf0, pf1;
            MKPF(p, 0, pf0) MKPF(p, 8, pf1)
            #pragma unroll
            for (int ct = 0; ct < 4; ++ct) {
                accB[ct] = __builtin_amdgcn_mfma_f32_32x32x16_bf16(va[ct],  pf0, accB[ct], 0, 0, 0);
                accB[ct] = __builtin_amdgcn_mfma_f32_32x32x16_bf16(vb2[ct], pf1, accB[ct], 0, 0, 0);
            }
        }
    }
    #undef MKPF

    // ---- 8-wave merge, bf16-packed slots ----
    #define SL_STORE(SL) { \
        ls[SL][0][lane] = l0; ls[SL][1][lane] = l1; \
        unsigned* sb = sm_u32 + (SL) * 4096; \
        _Pragma("unroll") for (int ct = 0; ct < 4; ++ct) \
        _Pragma("unroll") for (int i = 0; i < 8; ++i) { \
            sb[((ct) * 8 + i) * 64 + lane]     = pkt(accA[ct][2 * i], accA[ct][2 * i + 1]); \
            sb[((4 + ct) * 8 + i) * 64 + lane] = pkt(accB[ct][2 * i], accB[ct][2 * i + 1]); } }
    #define SL_ADD(SL) { \
        l0 += ls[SL][0][lane]; l1 += ls[SL][1][lane]; \
        unsigned* sb = sm_u32 + (SL) * 4096; \
        _Pragma("unroll") for (int ct = 0; ct < 4; ++ct) \
        _Pragma("unroll") for (int i = 0; i < 8; ++i) { \
            unsigned ua = sb[((ct) * 8 + i) * 64 + lane]; \
            accA[ct][2 * i]     += __builtin_bit_cast(float, ua << 16); \
            accA[ct][2 * i + 1] += __builtin_bit_cast(float, ua & 0xffff0000u); \
            unsigned ub = sb[((4 + ct) * 8 + i) * 64 + lane]; \
            accB[ct][2 * i]     += __builtin_bit_cast(float, ub << 16); \
            accB[ct][2 * i + 1] += __builtin_bit_cast(float, ub & 0xffff0000u); } }
    #define SL_RMW(SL) { \
        ls[SL][0][lane] += l0; ls[SL][1][lane] += l1; \
        unsigned* sb = sm_u32 + (SL) * 4096; \
        _Pragma("unroll") for (int ct = 0; ct < 4; ++ct) \
        _Pragma("unroll") for (int i = 0; i < 8; ++i) { \
            unsigned ua = sb[((ct) * 8 + i) * 64 + lane]; \
            float x0 = __builtin_bit_cast(float, ua << 16) + accA[ct][2 * i]; \
            float x1 = __builtin_bit_cast(float, ua & 0xffff0000u) + accA[ct][2 * i + 1]; \
            sb[((ct) * 8 + i) * 64 + lane] = pkt(x0, x1); \
            unsigned ub = sb[((4 + ct) * 8 + i) * 64 + lane]; \
            float y0 = __builtin_bit_cast(float, ub << 16) + accB[ct][2 * i]; \
            float y1 = __builtin_bit_cast(float, ub & 0xffff0000u) + accB[ct][2 * i + 1]; \
            sb[((4 + ct) * 8 + i) * 64 + lane] = pkt(y0, y1); } }

    if (wv == 4 || wv == 5) SL_STORE(wv - 4)
    __syncthreads();
    if (wv == 0 || wv == 1) SL_ADD(wv)
    __syncthreads();
    if (wv == 6 || wv == 7) SL_STORE(wv - 6)
    __syncthreads();
    if (wv == 2 || wv == 3) SL_RMW(wv - 2)
    __syncthreads();
    if (wv == 0 || wv == 1) SL_ADD(wv)
    __syncthreads();
    if (wv == 1) SL_STORE(0)
    __syncthreads();
    float* sf = (float*)sm_u32;
    if (wv == 0) {
        SL_ADD(0)
        #pragma unroll
        for (int ct = 0; ct < 4; ++ct)
            #pragma unroll
            for (int r = 0; r < 16; ++r) {
                sf[((ct) * 16 + r) * 64 + lane]     = accA[ct][r];
                sf[((4 + ct) * 16 + r) * 64 + lane] = accB[ct][r];
            }
        if (lane < 32) { invl[col] = 1.0f / l0; invl[32 + col] = 1.0f / l1; }
    }
    __syncthreads();
    #undef SL_STORE
    #undef SL_ADD
    #undef SL_RMW

    // ---- distributed coalesced writeback: 16 passes x 512 thr ----
    {
        const float g = gamma_p[0];
        const int n = tid & 63, ci = tid >> 6;
        const float il = invl[n];
        const int qs = n >> 5, nc = n & 31;
        #pragma unroll
        for (int p = 0; p < 16; ++p) {
            int ch = (p << 3) + ci;
            int ct = ch >> 5, chl = ch & 31;
            int h = (chl >> 2) & 1, r = (chl & 3) | ((chl >> 3) << 2);
            float val = sf[((qs * 4 + ct) * 16 + r) * 64 + nc + (h << 5)];
            size_t idx = ((size_t)(b * Cn + ch)) * Nn + q0 + n;
            out[idx] = g * (val * il) + x[idx];
        }
    }
}

// ---------------------------------------------------------------------------
extern "C" void kernel_launch(void* const* d_in, const int* in_sizes, int n_in,
                              void* d_out, int out_size, void* d_ws, size_t ws_size,
                              hipStream_t stream)
{
    const float* x     = (const float*)d_in[0];
    const float* Wq    = (const float*)d_in[1];
    const float* bq    = (const float*)d_in[2];
    const float* Wk    = (const float*)d_in[3];
    const float* bk    = (const float*)d_in[4];
    const float* Wv    = (const float*)d_in[5];
    const float* bv    = (const float*)d_in[6];
    const float* gamma = (const float*)d_in[7];
    float* out = (float*)d_out;

    unsigned short* ws16 = (unsigned short*)d_ws;
    unsigned short* qTw  = ws16;                              // 262144 u16
    unsigned short* kTw  = qTw + (size_t)Bn * Nn * C8n;       // 262144 u16
    unsigned short* vsww = kTw + (size_t)Bn * Nn * C8n;       // 2097152 u16

    qkv_kernel<<<dim3(256), dim3(256), 0, stream>>>(
        x, Wq, bq, Wk, bk, Wv, bv, qTw, kTw, vsww);

    attn_kernel<<<dim3(256), dim3(512), 0, stream>>>(
        qTw, kTw, vsww, x, gamma, out);
}

// Round 8
// 111.836 us; speedup vs baseline: 6.8564x; 1.0175x over previous
//
#include <hip/hip_runtime.h>
#include <math.h>

typedef __attribute__((ext_vector_type(8))) short bf16x8;
typedef __attribute__((ext_vector_type(16))) float f32x16;

constexpr int Bn = 4, Cn = 128, C8n = 16, Nn = 4096;

#if __has_builtin(__builtin_amdgcn_exp2f)
#define EXP2F(x) __builtin_amdgcn_exp2f(x)
#else
#define EXP2F(x) exp2f(x)
#endif

__device__ inline unsigned short f2bf(float f) {   // RTNE
    unsigned u = __builtin_bit_cast(unsigned, f);
    u += 0x7fff + ((u >> 16) & 1);
    return (unsigned short)(u >> 16);
}
__device__ inline unsigned pack2(float a, float b) {
    return (unsigned)f2bf(a) | ((unsigned)f2bf(b) << 16);
}
__device__ inline unsigned pkt(float a, float b) {  // truncating pack: lo=a, hi=b
#if __has_builtin(__builtin_amdgcn_perm)
    return __builtin_amdgcn_perm(__builtin_bit_cast(unsigned, b),
                                 __builtin_bit_cast(unsigned, a), 0x07060302u);
#else
    return (__builtin_bit_cast(unsigned, a) >> 16) |
           (__builtin_bit_cast(unsigned, b) & 0xffff0000u);
#endif
}

// ---------------------------------------------------------------------------
// Kernel 1: fused qkv projection GEMM (MFMA), reads x directly.
// (UNCHANGED from R6 — attribution: all deltas this round = attn.)
// ---------------------------------------------------------------------------
__global__ __launch_bounds__(256) void qkv_kernel(
    const float* __restrict__ x,
    const float* __restrict__ Wq, const float* __restrict__ bq,
    const float* __restrict__ Wk, const float* __restrict__ bk,
    const float* __restrict__ Wv, const float* __restrict__ bv,
    unsigned short* __restrict__ qT, unsigned short* __restrict__ kT,
    unsigned short* __restrict__ vsw)
{
    __shared__ unsigned short wlds[160 * 128];   // 40 KB: W bf16, swizzled rows
    __shared__ unsigned short v_s[128 * 64];     // 16 KB: [ch][n], swizzled
    __shared__ float qk_s[32][65];
    __shared__ float bfl[160];

    const int tid = threadIdx.x;
    const int b = blockIdx.x >> 6, n0 = (blockIdx.x & 63) << 6;
    const int w = tid >> 6, lane = tid & 63, col = lane & 31, half = lane >> 5;
    const float L2E = 1.4426950408889634f;

    {
        unsigned* wl32 = (unsigned*)wlds;
        for (int i = tid; i < 160 * 32; i += 256) {
            int r = i >> 5, cq = (i & 31) << 2;
            const float* src; float sc = 1.0f;
            if (r < 16)      { src = Wq + (size_t)r * Cn;        sc = L2E; }
            else if (r < 32) { src = Wk + (size_t)(r - 16) * Cn; }
            else             { src = Wv + (size_t)(r - 32) * Cn; }
            float4 t = *reinterpret_cast<const float4*>(&src[cq]);
            int G = cq >> 3;
            unsigned* wp = wl32 + 64 * r + 4 * (G ^ (r & 7)) + ((cq & 7) >> 1);
            wp[0] = pack2(t.x * sc, t.y * sc);
            wp[1] = pack2(t.z * sc, t.w * sc);
        }
        if (tid < 160)
            bfl[tid] = (tid < 16) ? bq[tid] * L2E
                     : (tid < 32) ? bk[tid - 16] : bv[tid - 32];
    }

    const int nx = n0 + ((w & 1) << 5);
    const float* xb = x + ((size_t)b * Cn) * Nn + nx + col;
    bf16x8 af[8];
    #pragma unroll
    for (int s = 0; s < 8; ++s) {
        float v[8];
        #pragma unroll
        for (int j = 0; j < 8; ++j)
            v[j] = xb[(size_t)(16 * s + 8 * half + j) * Nn];
        uint4 u = make_uint4(pack2(v[0], v[1]), pack2(v[2], v[3]),
                             pack2(v[4], v[5]), pack2(v[6], v[7]));
        af[s] = __builtin_bit_cast(bf16x8, u);
    }
    __syncthreads();                                        // barrier 1

    const int mb = (w >> 1) ? 3 : 0;
    const bool three = (w >> 1) == 0;
    f32x16 a0, a1, a2;
    {
        float b0 = bfl[32 * mb + col], b1 = bfl[32 * (mb + 1) + col];
        float b2v = three ? bfl[64 + col] : 0.0f;
        #pragma unroll
        for (int r = 0; r < 16; ++r) { a0[r] = b0; a1[r] = b1; a2[r] = b2v; }
    }
    #pragma unroll
    for (int s = 0; s < 8; ++s) {
        const int off = 8 * ((2 * s + half) ^ (col & 7));
        a0 = __builtin_amdgcn_mfma_f32_32x32x16_bf16(af[s],
             *(const bf16x8*)(wlds + 128 * (32 * mb + col) + off), a0, 0, 0, 0);
        a1 = __builtin_amdgcn_mfma_f32_32x32x16_bf16(af[s],
             *(const bf16x8*)(wlds + 128 * (32 * (mb + 1) + col) + off), a1, 0, 0, 0);
        if (three)
            a2 = __builtin_amdgcn_mfma_f32_32x32x16_bf16(af[s],
                 *(const bf16x8*)(wlds + 128 * (64 + col) + off), a2, 0, 0, 0);
    }

    unsigned* vp32 = (unsigned*)v_s;
    #define VS_WRITE(A, C0) { \
        const int c_ = (C0) + col; \
        _Pragma("unroll") for (int g = 0; g < 4; ++g) { \
            int Gn = ((w & 1) << 2) + g; \
            unsigned* up = vp32 + 32 * c_ + 4 * (Gn ^ (c_ & 7)) + (half << 1); \
            up[0] = pack2(A[4 * g],     A[4 * g + 1]); \
            up[1] = pack2(A[4 * g + 2], A[4 * g + 3]); } }

    if (w < 2) {
        #pragma unroll
        for (int r = 0; r < 16; ++r)
            qk_s[col][((w & 1) << 5) + (r & 3) + ((r >> 2) << 3) + (half << 2)] = a0[r];
        VS_WRITE(a1, 0)          // m=1 -> ch 0-31
        VS_WRITE(a2, 32)         // m=2 -> ch 32-63
    } else {
        VS_WRITE(a0, 64)         // m=3 -> ch 64-95
        VS_WRITE(a1, 96)         // m=4 -> ch 96-127
    }
    #undef VS_WRITE
    __syncthreads();                                        // barrier 2

    if (tid < 128) {
        int n = tid & 63, which = tid >> 6;
        unsigned wv_[8];
        #pragma unroll
        for (int i = 0; i < 8; ++i)
            wv_[i] = pack2(qk_s[16 * which + 2 * i][n], qk_s[16 * which + 2 * i + 1][n]);
        unsigned short* dst = (which ? kT : qT) + ((size_t)b * Nn + n0 + n) * C8n;
        *reinterpret_cast<uint4*>(dst)     = make_uint4(wv_[0], wv_[1], wv_[2], wv_[3]);
        *reinterpret_cast<uint4*>(dst + 8) = make_uint4(wv_[4], wv_[5], wv_[6], wv_[7]);
    }
    {
        const int ct = w, c_ = (ct << 5) + col;
        #pragma unroll
        for (int t = 0; t < 4; ++t) {
            int Gn = (t << 1) + half;
            bf16x8 fr = *(const bf16x8*)(vp32 + 32 * c_ + 4 * (Gn ^ (c_ & 7)));
            size_t o_ = ((((size_t)b * 256 + (n0 >> 4) + t) * 4 + ct) * 64 + lane) * 8;
            *reinterpret_cast<uint4*>(&vsw[o_]) = __builtin_bit_cast(uint4, fr);
        }
    }
}

// ---------------------------------------------------------------------------
// Kernel 2: attention. Block = 8 waves, 64 queries (2 q-subs), 8-way key split.
// R8 fix: permlane32_swap semantics are dst.row1 <-> src.row0 (ISA: "exchange
// the UPPER 32 lanes of the destination with the LOWER 32 lanes of the
// source"); R7 assumed row0<->row1 and failed. Correct call is (lo, hi):
//   r = swap(lo0, hi0): r[0] = {L<32: lo0(own);     L>=32: hi0(partner)} = u.x
//                       r[1] = {L<32: lo0(partner); L>=32: hi0(own)}     = u.z
// (matches HK's documented (lo, hi) call order with both results usable).
// ---------------------------------------------------------------------------
__global__ __launch_bounds__(512) void attn_kernel(
    const unsigned short* __restrict__ qT, const unsigned short* __restrict__ kT,
    const unsigned short* __restrict__ vsw, const float* __restrict__ x,
    const float* __restrict__ gamma_p, float* __restrict__ out)
{
    __shared__ unsigned sm_u32[8192];          // 32 KB: 2 bf16 slots / final f32
    __shared__ float ls[2][2][64];
    __shared__ float invl[64];

    const int tid = threadIdx.x, wv = tid >> 6, lane = tid & 63;
    const int col = lane & 31, half = lane >> 5;
    const int xcd = blockIdx.x & 7;
    const int b = xcd >> 1;
    const int q0 = ((((blockIdx.x >> 3) << 1) | (xcd & 1))) << 6;

    const unsigned short* qb = qT + (size_t)b * Nn * C8n;
    bf16x8 qf0 = *(const bf16x8*)&qb[(size_t)(q0 + col) * C8n + 8 * half];
    bf16x8 qf1 = *(const bf16x8*)&qb[(size_t)(q0 + 32 + col) * C8n + 8 * half];

    f32x16 accA[4], accB[4];
    #pragma unroll
    for (int ct = 0; ct < 4; ++ct) { accA[ct] = {}; accB[ct] = {}; }
    float l0 = 0.0f, l1 = 0.0f;        // per-half partial sums until post-loop
    const unsigned short* kb = kT + (size_t)b * Nn * C8n;

#if __has_builtin(__builtin_amdgcn_permlane32_swap)
    #define MKPF(P, O, F) { \
        unsigned lo0 = pkt(P[O], P[O + 1]), lo1 = pkt(P[O + 2], P[O + 3]); \
        unsigned hi0 = pkt(P[O + 4], P[O + 5]), hi1 = pkt(P[O + 6], P[O + 7]); \
        auto r0 = __builtin_amdgcn_permlane32_swap(lo0, hi0, false, false); \
        auto r1 = __builtin_amdgcn_permlane32_swap(lo1, hi1, false, false); \
        uint4 u_ = make_uint4(r0[0], r1[0], r0[1], r1[1]); \
        F = __builtin_bit_cast(bf16x8, u_); }
#else
    #define MKPF(P, O, F) { \
        unsigned lo0 = pkt(P[O], P[O + 1]), lo1 = pkt(P[O + 2], P[O + 3]); \
        unsigned hi0 = pkt(P[O + 4], P[O + 5]), hi1 = pkt(P[O + 6], P[O + 7]); \
        unsigned t0 = half ? lo0 : hi0, t1 = half ? lo1 : hi1; \
        unsigned r0 = (unsigned)__shfl_xor((int)t0, 32); \
        unsigned r1 = (unsigned)__shfl_xor((int)t1, 32); \
        uint4 u_ = make_uint4(half ? r0 : lo0, half ? r1 : lo1, \
                              half ? hi0 : r0, half ? hi1 : r1); \
        F = __builtin_bit_cast(bf16x8, u_); }
#endif

    #pragma unroll 1
    for (int kt = 0; kt < 16; ++kt) {
        const int j0 = (wv << 9) + (kt << 5);
        const size_t vbase = ((((size_t)b * 256 + (j0 >> 4)) * 4) * 64 + lane) * 8;
        bf16x8 va[4], vb2[4];
        #pragma unroll
        for (int ct = 0; ct < 4; ++ct) {
            va[ct]  = *(const bf16x8*)&vsw[vbase + (size_t)ct * 512];
            vb2[ct] = *(const bf16x8*)&vsw[vbase + (size_t)(4 + ct) * 512];
        }
        bf16x8 kf = *(const bf16x8*)&kb[(size_t)(j0 + col) * C8n + 8 * half];
        f32x16 z = {};

        // ---- q-sub A ----
        {
            f32x16 s = __builtin_amdgcn_mfma_f32_32x32x16_bf16(kf, qf0, z, 0, 0, 0);
            float p[16]; float ps = 0.0f;
            #pragma unroll
            for (int r = 0; r < 16; ++r) { p[r] = EXP2F(s[r]); ps += p[r]; }
            l0 += ps;                              // half-partial; reduced later
            bf16x8 pf0, pf1;
            MKPF(p, 0, pf0) MKPF(p, 8, pf1)
            __builtin_amdgcn_s_setprio(1);
            #pragma unroll
            for (int ct = 0; ct < 4; ++ct) {
                accA[ct] = __builtin_amdgcn_mfma_f32_32x32x16_bf16(va[ct],  pf0, accA[ct], 0, 0, 0);
                accA[ct] = __builtin_amdgcn_mfma_f32_32x32x16_bf16(vb2[ct], pf1, accA[ct], 0, 0, 0);
            }
            __builtin_amdgcn_s_setprio(0);
        }
        // ---- q-sub B ----
        {
            f32x16 s = __builtin_amdgcn_mfma_f32_32x32x16_bf16(kf, qf1, z, 0, 0, 0);
            float p[16]; float ps = 0.0f;
            #pragma unroll
            for (int r = 0; r < 16; ++r) { p[r] = EXP2F(s[r]); ps += p[r]; }
            l1 += ps;
            bf16x8 pf0, pf1;
            MKPF(p, 0, pf0) MKPF(p, 8, pf1)
            __builtin_amdgcn_s_setprio(1);
            #pragma unroll
            for (int ct = 0; ct < 4; ++ct) {
                accB[ct] = __builtin_amdgcn_mfma_f32_32x32x16_bf16(va[ct],  pf0, accB[ct], 0, 0, 0);
                accB[ct] = __builtin_amdgcn_mfma_f32_32x32x16_bf16(vb2[ct], pf1, accB[ct], 0, 0, 0);
            }
            __builtin_amdgcn_s_setprio(0);
        }
    }
    #undef MKPF

    // complete the deferred cross-half l reduction
    l0 += __shfl_xor(l0, 32);
    l1 += __shfl_xor(l1, 32);

    // ---- 8-wave merge, bf16-packed slots ----
    #define SL_STORE(SL) { \
        ls[SL][0][lane] = l0; ls[SL][1][lane] = l1; \
        unsigned* sb = sm_u32 + (SL) * 4096; \
        _Pragma("unroll") for (int ct = 0; ct < 4; ++ct) \
        _Pragma("unroll") for (int i = 0; i < 8; ++i) { \
            sb[((ct) * 8 + i) * 64 + lane]     = pkt(accA[ct][2 * i], accA[ct][2 * i + 1]); \
            sb[((4 + ct) * 8 + i) * 64 + lane] = pkt(accB[ct][2 * i], accB[ct][2 * i + 1]); } }
    #define SL_ADD(SL) { \
        l0 += ls[SL][0][lane]; l1 += ls[SL][1][lane]; \
        unsigned* sb = sm_u32 + (SL) * 4096; \
        _Pragma("unroll") for (int ct = 0; ct < 4; ++ct) \
        _Pragma("unroll") for (int i = 0; i < 8; ++i) { \
            unsigned ua = sb[((ct) * 8 + i) * 64 + lane]; \
            accA[ct][2 * i]     += __builtin_bit_cast(float, ua << 16); \
            accA[ct][2 * i + 1] += __builtin_bit_cast(float, ua & 0xffff0000u); \
            unsigned ub = sb[((4 + ct) * 8 + i) * 64 + lane]; \
            accB[ct][2 * i]     += __builtin_bit_cast(float, ub << 16); \
            accB[ct][2 * i + 1] += __builtin_bit_cast(float, ub & 0xffff0000u); } }
    #define SL_RMW(SL) { \
        ls[SL][0][lane] += l0; ls[SL][1][lane] += l1; \
        unsigned* sb = sm_u32 + (SL) * 4096; \
        _Pragma("unroll") for (int ct = 0; ct < 4; ++ct) \
        _Pragma("unroll") for (int i = 0; i < 8; ++i) { \
            unsigned ua = sb[((ct) * 8 + i) * 64 + lane]; \
            float x0 = __builtin_bit_cast(float, ua << 16) + accA[ct][2 * i]; \
            float x1 = __builtin_bit_cast(float, ua & 0xffff0000u) + accA[ct][2 * i + 1]; \
            sb[((ct) * 8 + i) * 64 + lane] = pkt(x0, x1); \
            unsigned ub = sb[((4 + ct) * 8 + i) * 64 + lane]; \
            float y0 = __builtin_bit_cast(float, ub << 16) + accB[ct][2 * i]; \
            float y1 = __builtin_bit_cast(float, ub & 0xffff0000u) + accB[ct][2 * i + 1]; \
            sb[((4 + ct) * 8 + i) * 64 + lane] = pkt(y0, y1); } }

    if (wv == 4 || wv == 5) SL_STORE(wv - 4)
    __syncthreads();
    if (wv == 0 || wv == 1) SL_ADD(wv)
    __syncthreads();
    if (wv == 6 || wv == 7) SL_STORE(wv - 6)
    __syncthreads();
    if (wv == 2 || wv == 3) SL_RMW(wv - 2)
    __syncthreads();
    if (wv == 0 || wv == 1) SL_ADD(wv)
    __syncthreads();
    if (wv == 1) SL_STORE(0)
    __syncthreads();
    float* sf = (float*)sm_u32;
    if (wv == 0) {
        SL_ADD(0)
        #pragma unroll
        for (int ct = 0; ct < 4; ++ct)
            #pragma unroll
            for (int r = 0; r < 16; ++r) {
                sf[((ct) * 16 + r) * 64 + lane]     = accA[ct][r];
                sf[((4 + ct) * 16 + r) * 64 + lane] = accB[ct][r];
            }
        if (lane < 32) { invl[col] = 1.0f / l0; invl[32 + col] = 1.0f / l1; }
    }
    __syncthreads();
    #undef SL_STORE
    #undef SL_ADD
    #undef SL_RMW

    // ---- distributed coalesced writeback: 16 passes x 512 thr ----
    {
        const float g = gamma_p[0];
        const int n = tid & 63, ci = tid >> 6;
        const float il = invl[n];
        const int qs = n >> 5, nc = n & 31;
        #pragma unroll
        for (int p = 0; p < 16; ++p) {
            int ch = (p << 3) + ci;
            int ct = ch >> 5, chl = ch & 31;
            int h = (chl >> 2) & 1, r = (chl & 3) | ((chl >> 3) << 2);
            float val = sf[((qs * 4 + ct) * 16 + r) * 64 + nc + (h << 5)];
            size_t idx = ((size_t)(b * Cn + ch)) * Nn + q0 + n;
            out[idx] = g * (val * il) + x[idx];
        }
    }
}

// ---------------------------------------------------------------------------
extern "C" void kernel_launch(void* const* d_in, const int* in_sizes, int n_in,
                              void* d_out, int out_size, void* d_ws, size_t ws_size,
                              hipStream_t stream)
{
    const float* x     = (const float*)d_in[0];
    const float* Wq    = (const float*)d_in[1];
    const float* bq    = (const float*)d_in[2];
    const float* Wk    = (const float*)d_in[3];
    const float* bk    = (const float*)d_in[4];
    const float* Wv    = (const float*)d_in[5];
    const float* bv    = (const float*)d_in[6];
    const float* gamma = (const float*)d_in[7];
    float* out = (float*)d_out;

    unsigned short* ws16 = (unsigned short*)d_ws;
    unsigned short* qTw  = ws16;                              // 262144 u16
    unsigned short* kTw  = qTw + (size_t)Bn * Nn * C8n;       // 262144 u16
    unsigned short* vsww = kTw + (size_t)Bn * Nn * C8n;       // 2097152 u16

    qkv_kernel<<<dim3(256), dim3(256), 0, stream>>>(
        x, Wq, bq, Wk, bk, Wv, bv, qTw, kTw, vsww);

    attn_kernel<<<dim3(256), dim3(512), 0, stream>>>(
        qTw, kTw, vsww, x, gamma, out);
}

// Round 9
// 107.703 us; speedup vs baseline: 7.1195x; 1.0384x over previous
//
#include <hip/hip_runtime.h>
#include <math.h>

typedef __attribute__((ext_vector_type(8))) short bf16x8;
typedef __attribute__((ext_vector_type(16))) float f32x16;

constexpr int Bn = 4, Cn = 128, C8n = 16, Nn = 4096;

#if __has_builtin(__builtin_amdgcn_exp2f)
#define EXP2F(x) __builtin_amdgcn_exp2f(x)
#else
#define EXP2F(x) exp2f(x)
#endif

__device__ inline unsigned short f2bf(float f) {   // RTNE
    unsigned u = __builtin_bit_cast(unsigned, f);
    u += 0x7fff + ((u >> 16) & 1);
    return (unsigned short)(u >> 16);
}
__device__ inline unsigned pack2(float a, float b) {
    return (unsigned)f2bf(a) | ((unsigned)f2bf(b) << 16);
}
__device__ inline unsigned pkt(float a, float b) {  // truncating pack: lo=a, hi=b
#if __has_builtin(__builtin_amdgcn_perm)
    return __builtin_amdgcn_perm(__builtin_bit_cast(unsigned, b),
                                 __builtin_bit_cast(unsigned, a), 0x07060302u);
#else
    return (__builtin_bit_cast(unsigned, a) >> 16) |
           (__builtin_bit_cast(unsigned, b) & 0xffff0000u);
#endif
}

// ---------------------------------------------------------------------------
// Kernel 1: fused qkv projection GEMM (MFMA).
// R9: m-split across gridDim.y for 2 blocks/CU (was 1 -> zero TLP).
//   y=0: m {0=qk, 1, 2}  (W rows 0..95,  LDS 24K) -> qT/kT + vsw ct0,ct1
//   y=1: m {3, 4}        (W rows 96..159, LDS 16K) -> vsw ct2,ct3
// Block 256 thr = 4 waves; waves (w>>1) split m-work, (w&1) = n-sub of 32.
// ---------------------------------------------------------------------------
__global__ __launch_bounds__(256) void qkv_kernel(
    const float* __restrict__ x,
    const float* __restrict__ Wq, const float* __restrict__ bq,
    const float* __restrict__ Wk, const float* __restrict__ bk,
    const float* __restrict__ Wv, const float* __restrict__ bv,
    unsigned short* __restrict__ qT, unsigned short* __restrict__ kT,
    unsigned short* __restrict__ vsw)
{
    __shared__ unsigned short wlds[96 * 128];    // 24 KB max (y=1 uses 64 rows)
    __shared__ unsigned short v_s[64 * 64];      // 8 KB: [64 local ch][64 n]
    __shared__ float qk_s[32][65];               // y=0 only
    __shared__ float bfl[96];

    const int tid = threadIdx.x;
    const int b = blockIdx.x >> 6, n0 = (blockIdx.x & 63) << 6;
    const int y = blockIdx.y;
    const int w = tid >> 6, lane = tid & 63, col = lane & 31, half = lane >> 5;
    const int g01 = w >> 1;
    const float L2E = 1.4426950408889634f;
    const int RBASE = y ? 96 : 0;
    const int RCNT  = y ? 64 : 96;

    // ---- A-frags first (issue x loads early; W staging overlaps) ----
    const int nx = n0 + ((w & 1) << 5);
    const float* xb = x + ((size_t)b * Cn) * Nn + nx + col;
    bf16x8 af[8];
    #pragma unroll
    for (int s = 0; s < 8; ++s) {
        float v[8];
        #pragma unroll
        for (int j = 0; j < 8; ++j)
            v[j] = xb[(size_t)(16 * s + 8 * half + j) * Nn];
        uint4 u = make_uint4(pack2(v[0], v[1]), pack2(v[2], v[3]),
                             pack2(v[4], v[5]), pack2(v[6], v[7]));
        af[s] = __builtin_bit_cast(bf16x8, u);
    }

    // ---- stage this y's W rows -> LDS (bf16, q rows scaled; XOR-swizzled) ----
    {
        unsigned* wl32 = (unsigned*)wlds;
        for (int i = tid; i < RCNT * 32; i += 256) {
            int rl = i >> 5, cq = (i & 31) << 2;
            int r = RBASE + rl;
            const float* src; float sc = 1.0f;
            if (r < 16)      { src = Wq + (size_t)r * Cn;        sc = L2E; }
            else if (r < 32) { src = Wk + (size_t)(r - 16) * Cn; }
            else             { src = Wv + (size_t)(r - 32) * Cn; }
            float4 t = *reinterpret_cast<const float4*>(&src[cq]);
            int G = cq >> 3;
            unsigned* wp = wl32 + 64 * rl + 4 * (G ^ (rl & 7)) + ((cq & 7) >> 1);
            wp[0] = pack2(t.x * sc, t.y * sc);
            wp[1] = pack2(t.z * sc, t.w * sc);
        }
        if (tid < RCNT) {
            int r = RBASE + tid;
            bfl[tid] = (r < 16) ? bq[r] * L2E
                     : (r < 32) ? bk[r - 16] : bv[r - 32];
        }
    }
    __syncthreads();                                        // barrier 1

    // ---- MFMA: local m assignment ----
    // y=0: g01=0 -> ml {0(qk), 1}; g01=1 -> ml {2}
    // y=1: g01=0 -> ml {0};        g01=1 -> ml {1}
    const int mlA = (y == 0) ? (g01 ? 2 : 0) : g01;
    const bool hasB = (y == 0) && (g01 == 0);
    f32x16 a0, a1;
    {
        float b0 = bfl[32 * mlA + col];
        float b1 = hasB ? bfl[32 + col] : 0.0f;
        #pragma unroll
        for (int r = 0; r < 16; ++r) { a0[r] = b0; a1[r] = b1; }
    }
    #pragma unroll
    for (int s = 0; s < 8; ++s) {
        const int off = 8 * ((2 * s + half) ^ (col & 7));
        a0 = __builtin_amdgcn_mfma_f32_32x32x16_bf16(af[s],
             *(const bf16x8*)(wlds + 128 * (32 * mlA + col) + off), a0, 0, 0, 0);
        if (hasB)
            a1 = __builtin_amdgcn_mfma_f32_32x32x16_bf16(af[s],
                 *(const bf16x8*)(wlds + 128 * (32 + col) + off), a1, 0, 0, 0);
    }

    // ---- write phase: qk -> qk_s (y=0), v -> v_s (local 64 ch) ----
    unsigned* vp32 = (unsigned*)v_s;
    #define VS_WRITE(A, C0) { \
        const int c_ = (C0) + col; \
        _Pragma("unroll") for (int g = 0; g < 4; ++g) { \
            int Gn = ((w & 1) << 2) + g; \
            unsigned* up = vp32 + 32 * c_ + 4 * (Gn ^ (c_ & 7)) + (half << 1); \
            up[0] = pack2(A[4 * g],     A[4 * g + 1]); \
            up[1] = pack2(A[4 * g + 2], A[4 * g + 3]); } }

    if (y == 0) {
        if (g01 == 0) {
            #pragma unroll
            for (int r = 0; r < 16; ++r)
                qk_s[col][((w & 1) << 5) + (r & 3) + ((r >> 2) << 3) + (half << 2)] = a0[r];
            VS_WRITE(a1, 0)          // m1 -> local ch 0-31  (global ct0)
        } else {
            VS_WRITE(a0, 32)         // m2 -> local ch 32-63 (global ct1)
        }
    } else {
        if (g01 == 0) { VS_WRITE(a0, 0)  }   // m3 -> ct2
        else          { VS_WRITE(a0, 32) }   // m4 -> ct3
    }
    #undef VS_WRITE
    __syncthreads();                                        // barrier 2

    // ---- exports ----
    if (y == 0 && tid < 128) {
        int n = tid & 63, which = tid >> 6;
        unsigned wv_[8];
        #pragma unroll
        for (int i = 0; i < 8; ++i)
            wv_[i] = pack2(qk_s[16 * which + 2 * i][n], qk_s[16 * which + 2 * i + 1][n]);
        unsigned short* dst = (which ? kT : qT) + ((size_t)b * Nn + n0 + n) * C8n;
        *reinterpret_cast<uint4*>(dst)     = make_uint4(wv_[0], wv_[1], wv_[2], wv_[3]);
        *reinterpret_cast<uint4*>(dst + 8) = make_uint4(wv_[4], wv_[5], wv_[6], wv_[7]);
    }
    {   // v fragments: waves (w&1)=local ct, (w>>1) picks tile pair
        const int ctl = w & 1, c_ = (ctl << 5) + col;
        const int tb = (w >> 1) << 1;
        #pragma unroll
        for (int tt = 0; tt < 2; ++tt) {
            int t = tb + tt;
            int Gn = (t << 1) + half;
            bf16x8 fr = *(const bf16x8*)(vp32 + 32 * c_ + 4 * (Gn ^ (c_ & 7)));
            size_t o_ = ((((size_t)b * 256 + (n0 >> 4) + t) * 4 + ((y << 1) | ctl)) * 64 + lane) * 8;
            *reinterpret_cast<uint4*>(&vsw[o_]) = __builtin_bit_cast(uint4, fr);
        }
    }
}

// ---------------------------------------------------------------------------
// Kernel 2: attention (R8 + K-prefetch: next iter's K fragment issued at loop
// top so the K->QK dependency is hidden under a full iteration).
// ---------------------------------------------------------------------------
__global__ __launch_bounds__(512) void attn_kernel(
    const unsigned short* __restrict__ qT, const unsigned short* __restrict__ kT,
    const unsigned short* __restrict__ vsw, const float* __restrict__ x,
    const float* __restrict__ gamma_p, float* __restrict__ out)
{
    __shared__ unsigned sm_u32[8192];          // 32 KB: 2 bf16 slots / final f32
    __shared__ float ls[2][2][64];
    __shared__ float invl[64];

    const int tid = threadIdx.x, wv = tid >> 6, lane = tid & 63;
    const int col = lane & 31, half = lane >> 5;
    const int xcd = blockIdx.x & 7;
    const int b = xcd >> 1;
    const int q0 = ((((blockIdx.x >> 3) << 1) | (xcd & 1))) << 6;

    const unsigned short* qb = qT + (size_t)b * Nn * C8n;
    bf16x8 qf0 = *(const bf16x8*)&qb[(size_t)(q0 + col) * C8n + 8 * half];
    bf16x8 qf1 = *(const bf16x8*)&qb[(size_t)(q0 + 32 + col) * C8n + 8 * half];

    f32x16 accA[4], accB[4];
    #pragma unroll
    for (int ct = 0; ct < 4; ++ct) { accA[ct] = {}; accB[ct] = {}; }
    float l0 = 0.0f, l1 = 0.0f;
    const unsigned short* kb = kT + (size_t)b * Nn * C8n;

#if __has_builtin(__builtin_amdgcn_permlane32_swap)
    #define MKPF(P, O, F) { \
        unsigned lo0 = pkt(P[O], P[O + 1]), lo1 = pkt(P[O + 2], P[O + 3]); \
        unsigned hi0 = pkt(P[O + 4], P[O + 5]), hi1 = pkt(P[O + 6], P[O + 7]); \
        auto r0 = __builtin_amdgcn_permlane32_swap(lo0, hi0, false, false); \
        auto r1 = __builtin_amdgcn_permlane32_swap(lo1, hi1, false, false); \
        uint4 u_ = make_uint4(r0[0], r1[0], r0[1], r1[1]); \
        F = __builtin_bit_cast(bf16x8, u_); }
#else
    #define MKPF(P, O, F) { \
        unsigned lo0 = pkt(P[O], P[O + 1]), lo1 = pkt(P[O + 2], P[O + 3]); \
        unsigned hi0 = pkt(P[O + 4], P[O + 5]), hi1 = pkt(P[O + 6], P[O + 7]); \
        unsigned t0 = half ? lo0 : hi0, t1 = half ? lo1 : hi1; \
        unsigned r0 = (unsigned)__shfl_xor((int)t0, 32); \
        unsigned r1 = (unsigned)__shfl_xor((int)t1, 32); \
        uint4 u_ = make_uint4(half ? r0 : lo0, half ? r1 : lo1, \
                              half ? hi0 : r0, half ? hi1 : r1); \
        F = __builtin_bit_cast(bf16x8, u_); }
#endif

    bf16x8 kf = *(const bf16x8*)&kb[(size_t)((wv << 9) + col) * C8n + 8 * half];

    #pragma unroll 1
    for (int kt = 0; kt < 16; ++kt) {
        const int j0 = (wv << 9) + (kt << 5);
        const int j0n = (wv << 9) + (((kt + 1) & 15) << 5);
        bf16x8 kf_next = *(const bf16x8*)&kb[(size_t)(j0n + col) * C8n + 8 * half];
        const size_t vbase = ((((size_t)b * 256 + (j0 >> 4)) * 4) * 64 + lane) * 8;
        bf16x8 va[4], vb2[4];
        #pragma unroll
        for (int ct = 0; ct < 4; ++ct) {
            va[ct]  = *(const bf16x8*)&vsw[vbase + (size_t)ct * 512];
            vb2[ct] = *(const bf16x8*)&vsw[vbase + (size_t)(4 + ct) * 512];
        }
        f32x16 z = {};

        // ---- q-sub A ----
        {
            f32x16 s = __builtin_amdgcn_mfma_f32_32x32x16_bf16(kf, qf0, z, 0, 0, 0);
            float p[16]; float ps = 0.0f;
            #pragma unroll
            for (int r = 0; r < 16; ++r) { p[r] = EXP2F(s[r]); ps += p[r]; }
            l0 += ps;
            bf16x8 pf0, pf1;
            MKPF(p, 0, pf0) MKPF(p, 8, pf1)
            __builtin_amdgcn_s_setprio(1);
            #pragma unroll
            for (int ct = 0; ct < 4; ++ct) {
                accA[ct] = __builtin_amdgcn_mfma_f32_32x32x16_bf16(va[ct],  pf0, accA[ct], 0, 0, 0);
                accA[ct] = __builtin_amdgcn_mfma_f32_32x32x16_bf16(vb2[ct], pf1, accA[ct], 0, 0, 0);
            }
            __builtin_amdgcn_s_setprio(0);
        }
        // ---- q-sub B ----
        {
            f32x16 s = __builtin_amdgcn_mfma_f32_32x32x16_bf16(kf, qf1, z, 0, 0, 0);
            float p[16]; float ps = 0.0f;
            #pragma unroll
            for (int r = 0; r < 16; ++r) { p[r] = EXP2F(s[r]); ps += p[r]; }
            l1 += ps;
            bf16x8 pf0, pf1;
            MKPF(p, 0, pf0) MKPF(p, 8, pf1)
            __builtin_amdgcn_s_setprio(1);
            #pragma unroll
            for (int ct = 0; ct < 4; ++ct) {
                accB[ct] = __builtin_amdgcn_mfma_f32_32x32x16_bf16(va[ct],  pf0, accB[ct], 0, 0, 0);
                accB[ct] = __builtin_amdgcn_mfma_f32_32x32x16_bf16(vb2[ct], pf1, accB[ct], 0, 0, 0);
            }
            __builtin_amdgcn_s_setprio(0);
        }
        kf = kf_next;
    }
    #undef MKPF

    l0 += __shfl_xor(l0, 32);
    l1 += __shfl_xor(l1, 32);

    // ---- 8-wave merge, bf16-packed slots ----
    #define SL_STORE(SL) { \
        ls[SL][0][lane] = l0; ls[SL][1][lane] = l1; \
        unsigned* sb = sm_u32 + (SL) * 4096; \
        _Pragma("unroll") for (int ct = 0; ct < 4; ++ct) \
        _Pragma("unroll") for (int i = 0; i < 8; ++i) { \
            sb[((ct) * 8 + i) * 64 + lane]     = pkt(accA[ct][2 * i], accA[ct][2 * i + 1]); \
            sb[((4 + ct) * 8 + i) * 64 + lane] = pkt(accB[ct][2 * i], accB[ct][2 * i + 1]); } }
    #define SL_ADD(SL) { \
        l0 += ls[SL][0][lane]; l1 += ls[SL][1][lane]; \
        unsigned* sb = sm_u32 + (SL) * 4096; \
        _Pragma("unroll") for (int ct = 0; ct < 4; ++ct) \
        _Pragma("unroll") for (int i = 0; i < 8; ++i) { \
            unsigned ua = sb[((ct) * 8 + i) * 64 + lane]; \
            accA[ct][2 * i]     += __builtin_bit_cast(float, ua << 16); \
            accA[ct][2 * i + 1] += __builtin_bit_cast(float, ua & 0xffff0000u); \
            unsigned ub = sb[((4 + ct) * 8 + i) * 64 + lane]; \
            accB[ct][2 * i]     += __builtin_bit_cast(float, ub << 16); \
            accB[ct][2 * i + 1] += __builtin_bit_cast(float, ub & 0xffff0000u); } }
    #define SL_RMW(SL) { \
        ls[SL][0][lane] += l0; ls[SL][1][lane] += l1; \
        unsigned* sb = sm_u32 + (SL) * 4096; \
        _Pragma("unroll") for (int ct = 0; ct < 4; ++ct) \
        _Pragma("unroll") for (int i = 0; i < 8; ++i) { \
            unsigned ua = sb[((ct) * 8 + i) * 64 + lane]; \
            float x0 = __builtin_bit_cast(float, ua << 16) + accA[ct][2 * i]; \
            float x1 = __builtin_bit_cast(float, ua & 0xffff0000u) + accA[ct][2 * i + 1]; \
            sb[((ct) * 8 + i) * 64 + lane] = pkt(x0, x1); \
            unsigned ub = sb[((4 + ct) * 8 + i) * 64 + lane]; \
            float y0 = __builtin_bit_cast(float, ub << 16) + accB[ct][2 * i]; \
            float y1 = __builtin_bit_cast(float, ub & 0xffff0000u) + accB[ct][2 * i + 1]; \
            sb[((4 + ct) * 8 + i) * 64 + lane] = pkt(y0, y1); } }

    if (wv == 4 || wv == 5) SL_STORE(wv - 4)
    __syncthreads();
    if (wv == 0 || wv == 1) SL_ADD(wv)
    __syncthreads();
    if (wv == 6 || wv == 7) SL_STORE(wv - 6)
    __syncthreads();
    if (wv == 2 || wv == 3) SL_RMW(wv - 2)
    __syncthreads();
    if (wv == 0 || wv == 1) SL_ADD(wv)
    __syncthreads();
    if (wv == 1) SL_STORE(0)
    __syncthreads();
    float* sf = (float*)sm_u32;
    if (wv == 0) {
        SL_ADD(0)
        #pragma unroll
        for (int ct = 0; ct < 4; ++ct)
            #pragma unroll
            for (int r = 0; r < 16; ++r) {
                sf[((ct) * 16 + r) * 64 + lane]     = accA[ct][r];
                sf[((4 + ct) * 16 + r) * 64 + lane] = accB[ct][r];
            }
        if (lane < 32) { invl[col] = 1.0f / l0; invl[32 + col] = 1.0f / l1; }
    }
    __syncthreads();
    #undef SL_STORE
    #undef SL_ADD
    #undef SL_RMW

    // ---- distributed coalesced writeback: 16 passes x 512 thr ----
    {
        const float g = gamma_p[0];
        const int n = tid & 63, ci = tid >> 6;
        const float il = invl[n];
        const int qs = n >> 5, nc = n & 31;
        #pragma unroll
        for (int p = 0; p < 16; ++p) {
            int ch = (p << 3) + ci;
            int ct = ch >> 5, chl = ch & 31;
            int h = (chl >> 2) & 1, r = (chl & 3) | ((chl >> 3) << 2);
            float val = sf[((qs * 4 + ct) * 16 + r) * 64 + nc + (h << 5)];
            size_t idx = ((size_t)(b * Cn + ch)) * Nn + q0 + n;
            out[idx] = g * (val * il) + x[idx];
        }
    }
}

// ---------------------------------------------------------------------------
extern "C" void kernel_launch(void* const* d_in, const int* in_sizes, int n_in,
                              void* d_out, int out_size, void* d_ws, size_t ws_size,
                              hipStream_t stream)
{
    const float* x     = (const float*)d_in[0];
    const float* Wq    = (const float*)d_in[1];
    const float* bq    = (const float*)d_in[2];
    const float* Wk    = (const float*)d_in[3];
    const float* bk    = (const float*)d_in[4];
    const float* Wv    = (const float*)d_in[5];
    const float* bv    = (const float*)d_in[6];
    const float* gamma = (const float*)d_in[7];
    float* out = (float*)d_out;

    unsigned short* ws16 = (unsigned short*)d_ws;
    unsigned short* qTw  = ws16;                              // 262144 u16
    unsigned short* kTw  = qTw + (size_t)Bn * Nn * C8n;       // 262144 u16
    unsigned short* vsww = kTw + (size_t)Bn * Nn * C8n;       // 2097152 u16

    qkv_kernel<<<dim3(256, 2), dim3(256), 0, stream>>>(
        x, Wq, bq, Wk, bk, Wv, bv, qTw, kTw, vsww);

    attn_kernel<<<dim3(256), dim3(512), 0, stream>>>(
        qTw, kTw, vsww, x, gamma, out);
}